// Round 14
// baseline (855.367 us; speedup 1.0000x reference)
//
#include <hip/hip_runtime.h>
#include <math.h>
#include <stdint.h>

#define Bn 4096
#define Mn 16
#define Dn 1024
#define FLATn 16384
#define HIDn 512
#define OUTn 128
#define NS_ITERS 14
#define PB 16
#define SSI 16

typedef __attribute__((ext_vector_type(8))) short short8;
typedef __attribute__((ext_vector_type(4))) float f32x4;

__device__ __forceinline__ void wsync(){
  asm volatile("" ::: "memory");
  __builtin_amdgcn_wave_barrier();
  asm volatile("" ::: "memory");
}

// pack 8 fp32 -> bf16 (RNE)
__device__ __forceinline__ void pack8hi(const float* sv, uint4& hv){
  uint32_t h[8];
  #pragma unroll
  for (int j=0;j<8;j++){
    uint32_t u = __float_as_uint(sv[j]);
    uint32_t th = u + 0x7FFFu + ((u>>16)&1u);
    h[j] = th>>16;
  }
  hv = make_uint4(h[0]|(h[1]<<16), h[2]|(h[3]<<16), h[4]|(h[5]<<16), h[6]|(h[7]<<16));
}

// pack 4 fp32 -> bf16 (RNE) into 2 u32
__device__ __forceinline__ void pack4hi(const float* sv, uint32_t& o0, uint32_t& o1){
  uint32_t h[4];
  #pragma unroll
  for (int j=0;j<4;j++){
    uint32_t u = __float_as_uint(sv[j]);
    uint32_t th = u + 0x7FFFu + ((u>>16)&1u);
    h[j] = th>>16;
  }
  o0 = h[0]|(h[1]<<16);
  o1 = h[2]|(h[3]<<16);
}

// ---------------- per-sample LayerNorm stats (standalone, for fallback) ----------------
__global__ __launch_bounds__(256) void k_stats(const float* __restrict__ x,
                                               const int* __restrict__ mask,
                                               float* __restrict__ mu,
                                               float* __restrict__ rinv,
                                               int* __restrict__ cnt) {
  int b = blockIdx.x;
  int t = threadIdx.x;
  __shared__ int s_m[Mn];
  __shared__ float red[16];
  if (t < Mn) s_m[t] = mask[b*Mn + t];
  __syncthreads();
  int c = 0;
  #pragma unroll
  for (int m=0;m<Mn;m++) c += s_m[m];
  const float4* xb = (const float4*)(x + (size_t)b*FLATn);
  float sum=0.f, sq=0.f;
  for (int i=t;i<FLATn/4;i+=256){
    int m = (i>>8);
    if (s_m[m]) {
      float4 v = xb[i];
      sum += v.x+v.y+v.z+v.w;
      sq  += v.x*v.x+v.y*v.y+v.z*v.z+v.w*v.w;
    }
  }
  for (int off=32;off>0;off>>=1){ sum += __shfl_down(sum,off); sq += __shfl_down(sq,off); }
  int wv = t>>6;
  if ((t&63)==0){ red[wv]=sum; red[wv+8]=sq; }
  __syncthreads();
  if (t==0){
    float S=red[0]+red[1]+red[2]+red[3];
    float Q=red[8]+red[9]+red[10]+red[11];
    float m_ = S/(float)FLATn;
    float v_ = Q/(float)FLATn - m_*m_;
    mu[b]=m_;
    rinv[b]=rsqrtf(v_+1e-5f);
    cnt[b]=c;
  }
}

// ================= FAST PATH (MFMA) =================

// fused: blocks [0,4096) = LN stats; blocks [4096,12288) = W conversion (bf16) + bias fold
__global__ __launch_bounds__(256) void k_pre(const float* __restrict__ x,
                                             const int* __restrict__ mask,
                                             float* __restrict__ mu,
                                             float* __restrict__ rinv,
                                             int* __restrict__ cnt,
                                             const float* __restrict__ w1,
                                             const float* __restrict__ w2,
                                             const float* __restrict__ g1,
                                             const float* __restrict__ g2,
                                             const float* __restrict__ be1,
                                             const float* __restrict__ be2,
                                             ushort* __restrict__ W16,
                                             float* __restrict__ biasP){
  __shared__ int s_m[Mn];
  __shared__ float red[16];
  __shared__ float sm[256];
  const int t = threadIdx.x;
  if (blockIdx.x < 4096){
    int b = blockIdx.x;
    if (t < Mn) s_m[t] = mask[b*Mn + t];
    __syncthreads();
    int c = 0;
    #pragma unroll
    for (int m=0;m<Mn;m++) c += s_m[m];
    const float4* xb = (const float4*)(x + (size_t)b*FLATn);
    float sum=0.f, sq=0.f;
    for (int i=t;i<FLATn/4;i+=256){
      int m = (i>>8);
      if (s_m[m]) {
        float4 v = xb[i];
        sum += v.x+v.y+v.z+v.w;
        sq  += v.x*v.x+v.y*v.y+v.z*v.z+v.w*v.w;
      }
    }
    for (int off=32;off>0;off>>=1){ sum += __shfl_down(sum,off); sq += __shfl_down(sq,off); }
    int wv = t>>6;
    if ((t&63)==0){ red[wv]=sum; red[wv+8]=sq; }
    __syncthreads();
    if (t==0){
      float S=red[0]+red[1]+red[2]+red[3];
      float Q=red[8]+red[9]+red[10]+red[11];
      float m_ = S/(float)FLATn;
      float v_ = Q/(float)FLATn - m_*m_;
      mu[b]=m_;
      rinv[b]=rsqrtf(v_+1e-5f);
      cnt[b]=c;
    }
  } else {
    const size_t TE = (size_t)HIDn*FLATn;
    const int idx2 = blockIdx.x - 4096;
    const int tower = idx2 >> 12;
    const int bxw = idx2 & 4095;
    const float* w = tower? w2 : w1;
    const float* g = tower? g2 : g1;
    const float* be = tower? be2 : be1;
    size_t idx = ((size_t)bxw*256 + t)*8;
    const int k = (int)(idx & (FLATn-1));
    float4 w0 = *(const float4*)(w + idx);
    float4 w1v = *(const float4*)(w + idx + 4);
    float4 g0 = *(const float4*)(g + k);
    float4 g1v = *(const float4*)(g + k + 4);
    float4 e0 = *(const float4*)(be + k);
    float4 e1v = *(const float4*)(be + k + 4);
    float a[8] = {w0.x*g0.x, w0.y*g0.y, w0.z*g0.z, w0.w*g0.w,
                  w1v.x*g1v.x, w1v.y*g1v.y, w1v.z*g1v.z, w1v.w*g1v.w};
    uint4 hv;
    pack8hi(a, hv);
    *(uint4*)(W16 + (size_t)tower*TE + idx) = hv;
    float s = w0.x*e0.x + w0.y*e0.y + w0.z*e0.z + w0.w*e0.w
            + w1v.x*e1v.x + w1v.y*e1v.y + w1v.z*e1v.z + w1v.w*e1v.w;
    sm[t] = s; __syncthreads();
    for (int off=128; off>0; off>>=1){
      if (t < off) sm[t] += sm[t+off];
      __syncthreads();
    }
    if (t==0){
      const int o = (int)(idx >> 14);
      atomicAdd(&biasP[tower*HIDn + o], sm[0]);
    }
  }
}

__device__ __forceinline__ void glds16(const void* g, void* l){
  __builtin_amdgcn_global_load_lds((const __attribute__((address_space(1))) uint32_t*)g,
                                   (__attribute__((address_space(3))) uint32_t*)l, 16, 0, 0);
}

// MFMA GEMM (BM=64, BN=512, BK=32, 8 waves 2m x 4n, wave tile 32x128), A+B dbuf,
// 72KB LDS -> 2 blocks/CU (cross-block latency hiding). Pure bf16 1-term.
// 512 blocks: bid&3=kc, (bid>>2)&1=tower, bid>>3=mi(0..63). [R7 schedule]
__global__ __launch_bounds__(512) void k_gemm1m(
    const float* __restrict__ x, const int* __restrict__ cnt,
    const float* __restrict__ mu, const float* __restrict__ rinv,
    const ushort* __restrict__ W16,
    float* __restrict__ hp){
  __shared__ uint4 A_lds[2][4][64];         // (buf, rb, lane) 8KB
  __shared__ uint4 B_lds[2][32][64];        // (buf, cb, lane) 64KB
  const int t = threadIdx.x;
  const int lane = t & 63;
  const int wid = t >> 6;
  const int wm = wid >> 2, wn = wid & 3;

  const int bid = blockIdx.x;
  const int kc = bid & 3;
  const int tower = (bid >> 2) & 1;
  const int mi = bid >> 3;
  const int b0 = mi*64;
  const size_t TE = (size_t)HIDn*FLATn;
  const ushort* Wb = W16 + (size_t)tower*TE;

  // A staging: thread -> (row r 0..63, seg 0..7 covering 4 k each)
  const int r = t>>3, seg = t&7;
  const int brow = b0 + r;
  const int cbr = cnt[brow];
  const float mur = mu[brow];
  const float rir = rinv[brow];
  const float* xrow = x + (size_t)brow*FLATn;
  const int rb_s = r>>4;
  const int lane_a = (r&15) + 16*(seg>>1);
  const int half_a = seg&1;

  f32x4 acc[2][8];
  #pragma unroll
  for (int i=0;i<2;i++)
    #pragma unroll
    for (int j=0;j<8;j++)
      acc[i][j] = (f32x4){0.f,0.f,0.f,0.f};

  auto loadA = [&](int kt, float* dst){   // dst[4]
    const int k0 = kc*4096 + kt*32;
    const int m = k0 >> 10;
    const int d0 = (k0 & 1023) + seg*4;
    const bool valid = m < cbr;
    int sm_ = tower ? (cbr-1-m) : m;
    if (!valid) sm_ = 0;
    const float* src = xrow + sm_*Dn + d0;
    float4 v = *(const float4*)(src);
    dst[0] = valid ? (v.x - mur)*rir : 0.f;
    dst[1] = valid ? (v.y - mur)*rir : 0.f;
    dst[2] = valid ? (v.z - mur)*rir : 0.f;
    dst[3] = valid ? (v.w - mur)*rir : 0.f;
  };

  auto writeA = [&](const float* sv, int buf){
    uint32_t u0, u1;
    pack4hi(sv, u0, u1);
    uint2* A2 = (uint2*)&A_lds[buf][0][0];
    A2[(rb_s*64 + lane_a)*2 + half_a] = make_uint2(u0, u1);
  };

  auto stageB = [&](int kt, int buf){
    const int k0 = kc*4096 + kt*32;
    const int col_l = lane & 15;
    const int kk_l = k0 + (lane>>4)*8;
    #pragma unroll
    for (int q=0;q<4;q++){
      int cb = wid*4 + q;         // 0..31
      const ushort* src = Wb + (size_t)(cb*16 + col_l)*FLATn + kk_l;
      glds16((const void*)src, (void*)&B_lds[buf][cb][0]);
    }
  };

  auto compute = [&](int buf){
    short8 ah[2];
    #pragma unroll
    for (int mf=0; mf<2; ++mf)
      ah[mf] = *(const short8*)&A_lds[buf][wm*2+mf][lane];
    #pragma unroll
    for (int nf=0; nf<8; ++nf){
      short8 bh = *(const short8*)&B_lds[buf][wn*8+nf][lane];
      #pragma unroll
      for (int mf=0; mf<2; ++mf)
        acc[mf][nf] = __builtin_amdgcn_mfma_f32_16x16x32_bf16(ah[mf], bh, acc[mf][nf], 0, 0, 0);
    }
  };

  float av[4], av2[4];
  loadA(0, av);
  writeA(av, 0);
  stageB(0, 0);
  loadA(1, av);
  __syncthreads();

  #pragma unroll 1
  for (int kt=0; kt<128; ++kt){
    const int cur = kt & 1;
    if (kt < 127){
      stageB(kt+1, cur^1);
      writeA(av, cur^1);
      if (kt < 126) loadA(kt+2, av2);
    }
    compute(cur);
    __syncthreads();
    if (kt < 126){
      #pragma unroll
      for (int j=0;j<4;j++) av[j]=av2[j];
    }
  }

  float* outp = hp + (size_t)(tower*4 + kc)*Bn*HIDn;
  #pragma unroll
  for (int mf=0; mf<2; ++mf){
    #pragma unroll
    for (int nf=0; nf<8; ++nf){
      int col = wn*128 + nf*16 + (lane&15);
      int rbase = b0 + wm*32 + mf*16 + ((lane>>4)<<2);
      #pragma unroll
      for (int rg=0; rg<4; ++rg)
        outp[(size_t)(rbase+rg)*HIDn + col] = acc[mf][nf][rg];
    }
  }
}

__global__ __launch_bounds__(256) void k_fix(const float* __restrict__ hp,
                                             const float* __restrict__ biasP,
                                             const float* __restrict__ ba1,
                                             const float* __restrict__ ba2,
                                             float* __restrict__ h1,
                                             float* __restrict__ h2){
  const int tower = blockIdx.y;
  size_t e = ((size_t)blockIdx.x*256 + threadIdx.x)*4;
  const size_t TS = (size_t)Bn*HIDn;
  const float* base = hp + (size_t)tower*4*TS;
  float4 s0 = *(const float4*)(base + e);
  float4 s1 = *(const float4*)(base + TS + e);
  float4 s2 = *(const float4*)(base + 2*TS + e);
  float4 s3 = *(const float4*)(base + 3*TS + e);
  int col = (int)(e & (HIDn-1));
  float4 bp = *(const float4*)(biasP + tower*HIDn + col);
  const float* ba = tower? ba2 : ba1;
  float4 bav = *(const float4*)(ba + col);
  float4 o;
  o.x = fmaxf(s0.x+s1.x+s2.x+s3.x+bp.x+bav.x, 0.f);
  o.y = fmaxf(s0.y+s1.y+s2.y+s3.y+bp.y+bav.y, 0.f);
  o.z = fmaxf(s0.z+s1.z+s2.z+s3.z+bp.z+bav.z, 0.f);
  o.w = fmaxf(s0.w+s1.w+s2.w+s3.w+bp.w+bav.w, 0.f);
  float* h = tower? h2 : h1;
  *(float4*)(h + e) = o;
}

// ================= FALLBACK big GEMM (fp32 VALU) =================
__global__ __launch_bounds__(256) void k_gemm1(
    const float* __restrict__ x, const int* __restrict__ cnt,
    const float* __restrict__ mu, const float* __restrict__ rinv,
    const float* __restrict__ g1, const float* __restrict__ be1,
    const float* __restrict__ w1, const float* __restrict__ bias1,
    const float* __restrict__ g2, const float* __restrict__ be2,
    const float* __restrict__ w2, const float* __restrict__ bias2,
    float* __restrict__ h1, float* __restrict__ h2) {
  const int tower = blockIdx.z;
  const float* g   = tower ? g2 : g1;
  const float* be  = tower ? be2 : be1;
  const float* w   = tower ? w2 : w1;
  const float* bia = tower ? bias2 : bias1;
  float* hout      = tower ? h2 : h1;

  __shared__ float As[32][128];
  __shared__ float Bs[32][64];

  const int t  = threadIdx.x;
  const int b0 = blockIdx.y * 128;
  const int o0 = blockIdx.x * 64;

  const int ar = t & 127;
  const int ah = t >> 7;
  const int brow = b0 + ar;
  const int cb = cnt[brow];
  const float mub = mu[brow];
  const float rb  = rinv[brow];
  const float* xrow = x + (size_t)brow * FLATn;

  const int bc = t & 63;
  const int bp = t >> 6;
  const float* wrow = w + (size_t)(o0 + bc) * FLATn;

  const int tx = t & 15, ty = t >> 4;
  const int c0 = tx*4, r0 = ty*8;

  float acc[8][4];
  #pragma unroll
  for (int i=0;i<8;i++){
    #pragma unroll
    for (int j=0;j<4;j++) acc[i][j]=0.f;
  }

  for (int kt=0; kt<FLATn/32; ++kt){
    const int k0 = kt*32;
    const int m  = k0 >> 10;
    const int d0 = k0 & 1023;
    {
      const int sm_ = tower ? (cb-1-m) : m;
      const bool valid = (m < cb);
      const float* src = xrow + sm_*Dn + d0 + ah*16;
      const float* gk  = g  + k0 + ah*16;
      const float* bk  = be + k0 + ah*16;
      #pragma unroll
      for (int q=0;q<4;q++){
        float4 v = valid ? *(const float4*)(src + q*4) : make_float4(0.f,0.f,0.f,0.f);
        float4 gg = *(const float4*)(gk + q*4);
        float4 bb = *(const float4*)(bk + q*4);
        int kk = ah*16 + q*4;
        As[kk+0][ar] = (v.x - mub)*rb*gg.x + bb.x;
        As[kk+1][ar] = (v.y - mub)*rb*gg.y + bb.y;
        As[kk+2][ar] = (v.z - mub)*rb*gg.z + bb.z;
        As[kk+3][ar] = (v.w - mub)*rb*gg.w + bb.w;
      }
    }
    {
      const float* srcw = wrow + k0 + bp*8;
      #pragma unroll
      for (int q=0;q<2;q++){
        float4 v = *(const float4*)(srcw + q*4);
        int kk = bp*8 + q*4;
        Bs[kk+0][bc]=v.x; Bs[kk+1][bc]=v.y; Bs[kk+2][bc]=v.z; Bs[kk+3][bc]=v.w;
      }
    }
    __syncthreads();
    #pragma unroll
    for (int kk=0;kk<32;kk++){
      float a[8], bb4[4];
      *(float4*)&a[0] = *(const float4*)&As[kk][r0];
      *(float4*)&a[4] = *(const float4*)&As[kk][r0+4];
      *(float4*)&bb4[0] = *(const float4*)&Bs[kk][c0];
      #pragma unroll
      for (int i=0;i<8;i++){
        #pragma unroll
        for (int j=0;j<4;j++) acc[i][j] += a[i]*bb4[j];
      }
    }
    __syncthreads();
  }
  float4 bv = *(const float4*)(bia + o0 + c0);
  #pragma unroll
  for (int i=0;i<8;i++){
    float4 ov;
    ov.x = fmaxf(acc[i][0]+bv.x, 0.f);
    ov.y = fmaxf(acc[i][1]+bv.y, 0.f);
    ov.z = fmaxf(acc[i][2]+bv.z, 0.f);
    ov.w = fmaxf(acc[i][3]+bv.w, 0.f);
    *(float4*)(hout + (size_t)(b0+r0+i)*HIDn + o0 + c0) = ov;
  }
}

// ---------------- second linear (+ fused batch-mean accumulation) ----------------
__global__ __launch_bounds__(256) void k_gemm2(
    const float* __restrict__ h1, const float* __restrict__ h2,
    const float* __restrict__ wb1, const float* __restrict__ bb1,
    const float* __restrict__ wb2, const float* __restrict__ bb2,
    float* __restrict__ F_H, float* __restrict__ F_G,
    float* __restrict__ muF) {
  const int tower = blockIdx.z;
  const float* A   = tower ? h2 : h1;
  const float* w   = tower ? wb2 : wb1;
  const float* bia = tower ? bb2 : bb1;
  float* F         = tower ? F_G : F_H;

  __shared__ float As[32][128];
  __shared__ float Bs[32][64];

  const int t  = threadIdx.x;
  const int b0 = blockIdx.y * 128;
  const int o0 = blockIdx.x * 64;

  const int ar = t & 127;
  const int ah = t >> 7;
  const float* arow = A + (size_t)(b0+ar)*HIDn;
  const int bc = t & 63;
  const int bp = t >> 6;
  const float* wrow = w + (size_t)(o0+bc)*HIDn;

  const int tx = t & 15, ty = t >> 4;
  const int c0 = tx*4, r0 = ty*8;

  float acc[8][4];
  #pragma unroll
  for (int i=0;i<8;i++){
    #pragma unroll
    for (int j=0;j<4;j++) acc[i][j]=0.f;
  }

  for (int kt=0; kt<HIDn/32; ++kt){
    const int k0 = kt*32;
    #pragma unroll
    for (int q=0;q<4;q++){
      float4 v = *(const float4*)(arow + k0 + ah*16 + q*4);
      int kk = ah*16+q*4;
      As[kk+0][ar]=v.x; As[kk+1][ar]=v.y; As[kk+2][ar]=v.z; As[kk+3][ar]=v.w;
    }
    #pragma unroll
    for (int q=0;q<2;q++){
      float4 v = *(const float4*)(wrow + k0 + bp*8 + q*4);
      int kk = bp*8+q*4;
      Bs[kk+0][bc]=v.x; Bs[kk+1][bc]=v.y; Bs[kk+2][bc]=v.z; Bs[kk+3][bc]=v.w;
    }
    __syncthreads();
    #pragma unroll
    for (int kk=0;kk<32;kk++){
      float a[8], bb4[4];
      *(float4*)&a[0] = *(const float4*)&As[kk][r0];
      *(float4*)&a[4] = *(const float4*)&As[kk][r0+4];
      *(float4*)&bb4[0] = *(const float4*)&Bs[kk][c0];
      #pragma unroll
      for (int i=0;i<8;i++){
        #pragma unroll
        for (int j=0;j<4;j++) acc[i][j] += a[i]*bb4[j];
      }
    }
    __syncthreads();
  }
  float4 bv = *(const float4*)(bia + o0 + c0);
  float cs[4];
  #pragma unroll
  for (int j=0;j<4;j++) cs[j]=0.f;
  #pragma unroll
  for (int i=0;i<8;i++){
    float4 ov;
    ov.x = acc[i][0]+bv.x;
    ov.y = acc[i][1]+bv.y;
    ov.z = acc[i][2]+bv.z;
    ov.w = acc[i][3]+bv.w;
    cs[0]+=ov.x; cs[1]+=ov.y; cs[2]+=ov.z; cs[3]+=ov.w;
    *(float4*)(F + (size_t)(b0+r0+i)*OUTn + o0 + c0) = ov;
  }
  float* red = &As[0][0];
  #pragma unroll
  for (int j=0;j<4;j++) red[ty*64 + c0 + j] = cs[j];
  __syncthreads();
  if (ty==0){
    #pragma unroll
    for (int j=0;j<4;j++){
      float tot=0.f;
      for (int q=0;q<16;q++) tot += red[q*64 + c0 + j];
      atomicAdd(&muF[tower*OUTn + o0 + c0 + j], tot);
    }
  }
}

// ---------------- covariance partials ----------------
__global__ __launch_bounds__(256) void k_covpart(const float* __restrict__ F_H,
                                                 const float* __restrict__ F_G,
                                                 float* __restrict__ covPart){
  const int s  = blockIdx.y;
  const int kc = blockIdx.x;
  const float* F1 = (s==1)? F_G : F_H;
  const float* F2 = (s==0)? F_H : F_G;
  __shared__ float A1[32][128], A2[32][128];
  const int t = threadIdx.x;
  const int tx = t & 15, ty = t >> 4;
  const int i0 = ty*8, j0 = tx*8;
  float acc[8][8];
  #pragma unroll
  for (int i=0;i<8;i++){
    #pragma unroll
    for (int j=0;j<8;j++) acc[i][j]=0.f;
  }
  const int kr = t >> 3;
  const int kp = (t & 7) * 16;
  for (int sub=0; sub<4; ++sub){
    const int kbase = kc*128 + sub*32;
    const float* p1 = F1 + (size_t)(kbase + kr)*OUTn + kp;
    const float* p2 = F2 + (size_t)(kbase + kr)*OUTn + kp;
    #pragma unroll
    for (int q=0;q<4;q++){
      *(float4*)&A1[kr][kp + q*4] = *(const float4*)(p1 + q*4);
      *(float4*)&A2[kr][kp + q*4] = *(const float4*)(p2 + q*4);
    }
    __syncthreads();
    #pragma unroll
    for (int kk=0;kk<32;kk++){
      float a[8], b[8];
      *(float4*)&a[0] = *(const float4*)&A1[kk][i0];
      *(float4*)&a[4] = *(const float4*)&A1[kk][i0+4];
      *(float4*)&b[0] = *(const float4*)&A2[kk][j0];
      *(float4*)&b[4] = *(const float4*)&A2[kk][j0+4];
      #pragma unroll
      for (int i=0;i<8;i++){
        #pragma unroll
        for (int j=0;j<8;j++) acc[i][j] += a[i]*b[j];
      }
    }
    __syncthreads();
  }
  float* outp = covPart + (size_t)(s*32 + kc)*OUTn*OUTn;
  #pragma unroll
  for (int i=0;i<8;i++){
    #pragma unroll
    for (int j=0;j<8;j+=4){
      *(float4*)(outp + (size_t)(i0+i)*OUTn + j0 + j) =
          make_float4(acc[i][j],acc[i][j+1],acc[i][j+2],acc[i][j+3]);
    }
  }
}

// muF holds column SUMS (not means)
__global__ __launch_bounds__(256) void k_sigma(const float* __restrict__ covPart,
                                               const float* __restrict__ muF,
                                               float* __restrict__ Sigma){
  const int s = blockIdx.y;
  const int e = blockIdx.x*256 + threadIdx.x;
  const int i = e >> 7, j = e & 127;
  float acc = 0.f;
  for (int c=0;c<32;c++) acc += covPart[(size_t)(s*32+c)*16384 + e];
  const float* mu1 = muF + ((s==1)? 128 : 0);
  const float* mu2 = muF + ((s==0)? 0 : 128);
  float v = (acc - mu1[i]*mu2[j]*(1.0f/(float)Bn)) * (1.0f/(float)(Bn-1));
  if (s < 2 && i==j) v += 1e-4f;
  Sigma[(size_t)s*16384 + e] = v;
}

// ---------------- Newton-Schulz prep ----------------
__global__ __launch_bounds__(256) void k_nsprep(const float* __restrict__ Sigma,
                                                float* __restrict__ Yb,
                                                float* __restrict__ Zb,
                                                float* __restrict__ cval){
  const int s = blockIdx.x;
  const float* A = Sigma + (size_t)s*16384;
  __shared__ float As[16384];
  __shared__ float v[128], w[128];
  __shared__ float sh[4];
  const int t = threadIdx.x;
  for (int i=t;i<16384;i+=256) As[i]=A[i];
  if (t<128) v[t]=1.f;
  __syncthreads();
  float lam = 1.f;
  for (int it=0; it<12; ++it){
    const int i = t>>1, hf = t&1;
    float ss=0.f;
    const float* Ai = &As[i*128];
    for (int q=hf*64;q<hf*64+64;q++) ss += Ai[q]*v[q];
    ss += __shfl_xor(ss,1);
    if (hf==0) w[i]=ss;
    __syncthreads();
    if (t==0){
      float n2=0.f;
      for (int q2=0;q2<128;q2++) n2 += w[q2]*w[q2];
      sh[0] = sqrtf(n2);
    }
    __syncthreads();
    const float nrm = sh[0];
    lam = nrm;
    if (t<128) v[t] = w[t] / fmaxf(nrm, 1e-30f);
    __syncthreads();
  }
  const float c = 1.05f*lam + 1e-20f;
  const float invc = 1.f/c;
  float* Yp = Yb + (size_t)s*16384;
  float* Zp = Zb + (size_t)s*16384;
  for (int i=t;i<16384;i+=256){
    Yp[i] = As[i]*invc;
    Zp[i] = ((i>>7)==(i&127)) ? 1.f : 0.f;
  }
  if (t==0) cval[s]=c;
}

// ---------------- NS retiled: 32x32 C-tiles ----------------
__global__ __launch_bounds__(256) void k_ns1b(const float* __restrict__ Yb,
                                              const float* __restrict__ Zb,
                                              float* __restrict__ Tb){
  const int s = blockIdx.z;
  const float* Y = Yb + (size_t)s*16384;
  const float* Z = Zb + (size_t)s*16384;
  float* T = Tb + (size_t)s*16384;
  const int r0 = blockIdx.y*32, c0 = blockIdx.x*32;
  __shared__ float As[32][132];
  __shared__ float Bs[128][32];
  const int t = threadIdx.x;
  #pragma unroll
  for (int q=0;q<4;q++){
    int i = q*1024 + t*4;
    int row = i>>7, colx = i&127;
    *(float4*)&As[row][colx] = *(const float4*)(Z + (size_t)(r0+row)*128 + colx);
    int k = i>>5, cc = i&31;
    *(float4*)&Bs[k][cc] = *(const float4*)(Y + (size_t)k*128 + c0 + cc);
  }
  __syncthreads();
  const int r = t>>3, cg = t&7;
  float acc[4] = {0.f,0.f,0.f,0.f};
  #pragma unroll
  for (int k4=0;k4<32;k4++){
    float4 a4 = *(const float4*)&As[r][k4*4];
    float aa[4] = {a4.x,a4.y,a4.z,a4.w};
    #pragma unroll
    for (int kk=0;kk<4;kk++){
      float4 b = *(const float4*)&Bs[k4*4+kk][cg*4];
      acc[0] += aa[kk]*b.x; acc[1] += aa[kk]*b.y;
      acc[2] += aa[kk]*b.z; acc[3] += aa[kk]*b.w;
    }
  }
  const int gr = r0 + r;
  const int gc = c0 + cg*4;
  float4 o;
  o.x = ((gr==gc+0)?3.f:0.f) - acc[0];
  o.y = ((gr==gc+1)?3.f:0.f) - acc[1];
  o.z = ((gr==gc+2)?3.f:0.f) - acc[2];
  o.w = ((gr==gc+3)?3.f:0.f) - acc[3];
  *(float4*)(T + (size_t)gr*128 + gc) = o;
}

__global__ __launch_bounds__(256) void k_ns2b(const float* __restrict__ Yb,
                                              const float* __restrict__ Zb,
                                              const float* __restrict__ Tb,
                                              float* __restrict__ Ynb,
                                              float* __restrict__ Znb){
  const int s = blockIdx.z;
  const int which = blockIdx.y >> 2;
  const int r0 = (blockIdx.y & 3)*32, c0 = blockIdx.x*32;
  const float* Am = which ? (Tb + (size_t)s*16384) : (Yb + (size_t)s*16384);
  const float* Bm = which ? (Zb + (size_t)s*16384) : (Tb + (size_t)s*16384);
  float* C = which ? (Znb + (size_t)s*16384) : (Ynb + (size_t)s*16384);
  __shared__ float As[32][132];
  __shared__ float Bs[128][32];
  const int t = threadIdx.x;
  #pragma unroll
  for (int q=0;q<4;q++){
    int i = q*1024 + t*4;
    int row = i>>7, colx = i&127;
    *(float4*)&As[row][colx] = *(const float4*)(Am + (size_t)(r0+row)*128 + colx);
    int k = i>>5, cc = i&31;
    *(float4*)&Bs[k][cc] = *(const float4*)(Bm + (size_t)k*128 + c0 + cc);
  }
  __syncthreads();
  const int r = t>>3, cg = t&7;
  float acc[4] = {0.f,0.f,0.f,0.f};
  #pragma unroll
  for (int k4=0;k4<32;k4++){
    float4 a4 = *(const float4*)&As[r][k4*4];
    float aa[4] = {a4.x,a4.y,a4.z,a4.w};
    #pragma unroll
    for (int kk=0;kk<4;kk++){
      float4 b = *(const float4*)&Bs[k4*4+kk][cg*4];
      acc[0] += aa[kk]*b.x; acc[1] += aa[kk]*b.y;
      acc[2] += aa[kk]*b.z; acc[3] += aa[kk]*b.w;
    }
  }
  float4 o = make_float4(0.5f*acc[0], 0.5f*acc[1], 0.5f*acc[2], 0.5f*acc[3]);
  *(float4*)(C + (size_t)(r0+r)*128 + c0 + cg*4) = o;
}

__device__ __forceinline__ void mm_acc16(const float* __restrict__ Arow,
                                         const float* __restrict__ Bs,
                                         int c0, float* acc){
  for (int k4=0;k4<128;k4+=4){
    float4 av = *(const float4*)(Arow + k4);
    float aa[4] = {av.x, av.y, av.z, av.w};
    #pragma unroll
    for (int kk=0;kk<4;kk++){
      const float a = aa[kk];
      const float* bp = &Bs[(k4+kk)*128 + c0];
      const float4 b0 = *(const float4*)(bp);
      const float4 b1 = *(const float4*)(bp+4);
      const float4 b2 = *(const float4*)(bp+8);
      const float4 b3 = *(const float4*)(bp+12);
      acc[0]+=a*b0.x;  acc[1]+=a*b0.y;  acc[2]+=a*b0.z;  acc[3]+=a*b0.w;
      acc[4]+=a*b1.x;  acc[5]+=a*b1.y;  acc[6]+=a*b1.z;  acc[7]+=a*b1.w;
      acc[8]+=a*b2.x;  acc[9]+=a*b2.y;  acc[10]+=a*b2.z; acc[11]+=a*b2.w;
      acc[12]+=a*b3.x; acc[13]+=a*b3.y; acc[14]+=a*b3.z; acc[15]+=a*b3.w;
    }
  }
}

__global__ __launch_bounds__(256) void k_mm(const float* __restrict__ Am,
                                            const float* __restrict__ Bm,
                                            float* __restrict__ C,
                                            const float* __restrict__ cval,
                                            const int useScale,
                                            float* __restrict__ out2){
  __shared__ float Bs[16384];
  const int t = threadIdx.x;
  for (int i=t;i<16384;i+=256) Bs[i]=Bm[i];
  __syncthreads();
  const int r = blockIdx.x*32 + (t>>3);
  const int c0 = (t&7)*16;
  float acc[16];
  #pragma unroll
  for (int j=0;j<16;j++) acc[j]=0.f;
  mm_acc16(Am + (size_t)r*128, Bs, c0, acc);
  const float scale = useScale ? rsqrtf(cval[0]*cval[1]) : 1.f;
  float* Cr = C + (size_t)r*128 + c0;
  #pragma unroll
  for (int j=0;j<16;j++) Cr[j] = acc[j]*scale;
  if (out2 != nullptr){
    float* Or = out2 + (size_t)r*128 + c0;
    #pragma unroll
    for (int j=0;j<16;j++) Or[j] = acc[j]*scale;
  }
}

// ---------------- fused E=T^T T + top-10 sqrt-eigenvalues via subspace iteration ----------------
__device__ __forceinline__ void pairpq(int k, int rr, int& p, int& q){
  if (k==0){ p = 15; q = rr % 15; }
  else { p = (rr + k) % 15; q = (rr + 15 - k) % 15; }
}

__global__ __launch_bounds__(1024) void k_final3(const float* __restrict__ Tmat,
                                                 float* __restrict__ outp){
  __shared__ float Es[128*132];
  __shared__ float Tt[128*132];
  __shared__ float Vt[PB*132];
  __shared__ float Wt[PB*132];
  __shared__ float GP[PB*PB*4];
  __shared__ float Gs[PB*17];
  __shared__ float Ls[PB*17];
  __shared__ float rLs[PB];
  __shared__ float Ms[PB*17];
  __shared__ float cs_[8], sn_[8];
  __shared__ float scoreSh;

  const int t = threadIdx.x;
  for (int i=t;i<16384;i+=1024)
    Tt[(i>>7)*132 + (i&127)] = Tmat[i];
  for (int i=t;i<PB*128;i+=1024){
    uint32_t u = (uint32_t)i*2654435761u + 0x9E3779B9u;
    u ^= u>>16; u *= 0x85EBCA6Bu; u ^= u>>13;
    float rv = ((float)(u & 0xFFFF) - 32768.0f) * (1.0f/32768.0f);
    Vt[(i>>7)*132 + (i&127)] = rv;
  }
  __syncthreads();

  // E = T^T @ T
  {
    const int ei = t>>3, ej0 = (t&7)*16;
    float ea[16];
    #pragma unroll
    for (int j=0;j<16;j++) ea[j]=0.f;
    for (int k=0;k<128;k++){
      float a = Tt[k*132 + ei];
      #pragma unroll
      for (int j=0;j<16;j+=4){
        float4 b = *(const float4*)&Tt[k*132 + ej0 + j];
        ea[j]+=a*b.x; ea[j+1]+=a*b.y; ea[j+2]+=a*b.z; ea[j+3]+=a*b.w;
      }
    }
    #pragma unroll
    for (int j=0;j<16;j++) Es[ei*132 + ej0 + j] = ea[j];
  }
  __syncthreads();

  const int c  = t & 15;
  const int r0 = t >> 4;
  const int gi = t >> 6;
  const int gj = (t >> 2) & 15;
  const int gq = t & 3;

  for (int it=0; it<=SSI; ++it){
    float a0=0.f, a1=0.f;
    {
      const float* vr = &Vt[c*132];
      const float* e0 = &Es[r0*132];
      const float* e1 = &Es[(r0+64)*132];
      #pragma unroll
      for (int k4=0;k4<32;k4++){
        float4 vv = *(const float4*)(vr + k4*4);
        float4 x0 = *(const float4*)(e0 + k4*4);
        float4 x1 = *(const float4*)(e1 + k4*4);
        a0 += x0.x*vv.x + x0.y*vv.y + x0.z*vv.z + x0.w*vv.w;
        a1 += x1.x*vv.x + x1.y*vv.y + x1.z*vv.z + x1.w*vv.w;
      }
    }
    Wt[c*132 + r0] = a0;
    Wt[c*132 + r0 + 64] = a1;
    __syncthreads();

    if (it == SSI) break;

    {
      float s = 0.f;
      const float* wi = &Wt[gi*132 + gq*32];
      const float* wj = &Wt[gj*132 + gq*32];
      #pragma unroll
      for (int k4=0;k4<8;k4++){
        float4 va = *(const float4*)(wi + k4*4);
        float4 vb = *(const float4*)(wj + k4*4);
        s += va.x*vb.x + va.y*vb.y + va.z*vb.z + va.w*vb.w;
      }
      GP[(gi*16+gj)*4 + gq] = s;
    }
    __syncthreads();
    if (t < 256){
      int i = t>>4, j = t&15;
      float g = GP[(i*16+j)*4+0]+GP[(i*16+j)*4+1]+GP[(i*16+j)*4+2]+GP[(i*16+j)*4+3];
      if (i==j) g *= 1.0000012f;
      Gs[i*17+j] = g;
    }
    __syncthreads();

    if (t < 64){
      const int j = t & 15;
      float g[PB], l[PB];
      #pragma unroll
      for (int i=0;i<PB;i++) g[i] = Gs[j*17+i];
      const float g00 = Gs[0];
      const float floorv = fmaxf(1e-12f*g00, 1e-30f);
      #pragma unroll
      for (int k=0;k<PB;k++){
        float dkk = __shfl(g[k], k);
        dkk = sqrtf(fmaxf(dkk, floorv));
        float ljk = g[k] / dkk;
        l[k] = ljk;
        #pragma unroll
        for (int i2=0;i2<PB;i2++){
          if (i2 > k) g[i2] -= ljk * __shfl(ljk, i2);
        }
      }
      if (t < 16){
        #pragma unroll
        for (int k=0;k<PB;k++) Ls[j*17+k] = (k<=j)? l[k] : 0.f;
        rLs[j] = 1.f / l[j];
      }
    }
    __syncthreads();

    if (t < 128){
      const int r = t;
      float w[PB], y[PB];
      #pragma unroll
      for (int i=0;i<PB;i++) w[i] = Wt[i*132 + r];
      #pragma unroll
      for (int i=0;i<PB;i++){
        float a = w[i];
        #pragma unroll
        for (int q2=0;q2<PB;q2++){
          if (q2 < i) a -= Ls[i*17+q2] * y[q2];
        }
        y[i] = a * rLs[i];
      }
      #pragma unroll
      for (int i=0;i<PB;i++) Vt[i*132 + r] = y[i];
    }
    __syncthreads();
  }

  {
    float s = 0.f;
    const float* vi = &Vt[gi*132 + gq*32];
    const float* wj = &Wt[gj*132 + gq*32];
    #pragma unroll
    for (int k4=0;k4<8;k4++){
      float4 va = *(const float4*)(vi + k4*4);
      float4 vb = *(const float4*)(wj + k4*4);
      s += va.x*vb.x + va.y*vb.y + va.z*vb.z + va.w*vb.w;
    }
    GP[(gi*16+gj)*4 + gq] = s;
  }
  __syncthreads();
  if (t < 256){
    int i = t>>4, j = t&15;
    Gs[i*17+j] = GP[(i*16+j)*4+0]+GP[(i*16+j)*4+1]+GP[(i*16+j)*4+2]+GP[(i*16+j)*4+3];
  }
  __syncthreads();
  if (t < 256){
    int i = t>>4, j = t&15;
    Ms[i*17+j] = 0.5f*(Gs[i*17+j] + Gs[j*17+i]);
  }
  __syncthreads();

  if (t < 64){
    volatile float* M = Ms;
    const int c16 = t & 15;
    const int kk0 = t >> 4;
    for (int sweep=0; sweep<7; ++sweep){
      for (int rr=0; rr<15; ++rr){
        if (t < 8){
          int p, q; pairpq(t, rr, p, q);
          float app = M[p*17+p], aqq = M[q*17+q], apq = M[p*17+q];
          float cc=1.f, ss=0.f;
          float denom = fabsf(app)+fabsf(aqq);
          if (fabsf(apq) > 1e-12f*denom + 1e-32f){
            float tau = (aqq - app) / (2.f*apq);
            float tt = ((tau>=0.f)?1.f:-1.f) / (fabsf(tau) + sqrtf(1.f + tau*tau));
            cc = rsqrtf(1.f + tt*tt);
            ss = tt*cc;
          }
          cs_[t] = cc; sn_[t] = ss;
        }
        wsync();
        #pragma unroll
        for (int kx=0; kx<2; kx++){
          int k = kk0 + kx*4;
          int p, q; pairpq(k, rr, p, q);
          float cc = cs_[k], ss = sn_[k];
          float mp = M[p*17+c16], mq = M[q*17+c16];
          M[p*17+c16] = cc*mp - ss*mq;
          M[q*17+c16] = ss*mp + cc*mq;
        }
        wsync();
        #pragma unroll
        for (int kx=0; kx<2; kx++){
          int k = kk0 + kx*4;
          int p, q; pairpq(k, rr, p, q);
          float cc = cs_[k], ss = sn_[k];
          float mp = M[c16*17+p], mq = M[c16*17+q];
          M[c16*17+p] = cc*mp - ss*mq;
          M[c16*17+q] = ss*mp + cc*mq;
        }
        wsync();
      }
    }
    if (t < 16){
      float di = M[t*17+t];
      int cnt2 = 0;
      #pragma unroll
      for (int j=0;j<16;j++){
        float dj = M[j*17+j];
        cnt2 += (dj > di || (dj == di && j < t)) ? 1 : 0;
      }
      float qc = (cnt2 < 10) ? sqrtf(fmaxf(di, 0.f)) : 0.f;
      #pragma unroll
      for (int off=8;off>0;off>>=1) qc += __shfl_down(qc, off);
      if (t==0){
        float qv = qc * 0.1f;
        scoreSh = 1.f/(1.f+expf(-qv));
      }
    }
  }
  __syncthreads();
  const float sc = scoreSh;
  for (int i=t;i<Bn;i+=1024) outp[i] = sc;
}

extern "C" void kernel_launch(void* const* d_in, const int* in_sizes, int n_in,
                              void* d_out, int out_size, void* d_ws, size_t ws_size,
                              hipStream_t stream) {
  (void)in_sizes; (void)n_in; (void)out_size;
  const float* x     = (const float*)d_in[0];
  const int*   mask  = (const int*)d_in[1];
  const float* ln1_g = (const float*)d_in[2];
  const float* ln1_b = (const float*)d_in[3];
  const float* w1a   = (const float*)d_in[4];
  const float* b1a   = (const float*)d_in[5];
  const float* w1b   = (const float*)d_in[6];
  const float* b1b   = (const float*)d_in[7];
  const float* ln2_g = (const float*)d_in[8];
  const float* ln2_b = (const float*)d_in[9];
  const float* w2a   = (const float*)d_in[10];
  const float* b2a   = (const float*)d_in[11];
  const float* w2b   = (const float*)d_in[12];
  const float* b2b   = (const float*)d_in[13];
  float* out = (float*)d_out;

  char* ws = (char*)d_ws;
  float* mu      = (float*)(ws);
  float* rinv    = (float*)(ws + (16<<10));
  int*   cnt     = (int*)  (ws + (32<<10));
  float* muF     = (float*)(ws + (48<<10));
  float* cval    = (float*)(ws + (52<<10));
  float* biasP   = (float*)(ws + (56<<10));
  float* Sigma   = (float*)(ws + (128<<10));
  const size_t nsOff = (size_t)512<<10;
  float* nsY0 = (float*)(ws + nsOff);
  float* nsY1 = (float*)(ws + nsOff + (128<<10));
  float* nsZ0 = (float*)(ws + nsOff + (256<<10));
  float* nsZ1 = (float*)(ws + nsOff + (384<<10));
  float* nsT  = (float*)(ws + nsOff + (512<<10));
  float* tmpM = (float*)(ws + nsOff + (640<<10));
  float* Tmat = (float*)(ws + nsOff + (704<<10));
  float* F_H  = (float*)(ws + ((size_t)2<<20));
  float* F_G  = (float*)(ws + ((size_t)4<<20));
  float* h1   = (float*)(ws + ((size_t)6<<20));
  float* h2   = (float*)(ws + ((size_t)14<<20));
  float* covPart = (float*)(ws + ((size_t)6<<20));
  float*  hp  = (float*)(ws + ((size_t)24<<20));
  ushort* W16 = (ushort*)(ws + ((size_t)88<<20));

  const bool fast = ws_size >= ((size_t)153<<20);

  // zero muF (col-sum accumulators), cval, biasP
  hipMemsetAsync((void*)(ws + (48<<10)), 0, (12<<10), stream);

  if (fast){
    k_pre<<<12288, 256, 0, stream>>>(x, mask, mu, rinv, cnt,
        w1a, w2a, ln1_g, ln2_g, ln1_b, ln2_b, W16, biasP);
    k_gemm1m<<<512, 512, 0, stream>>>(x, cnt, mu, rinv, W16, hp);
    k_fix<<<dim3(2048,2), 256, 0, stream>>>(hp, biasP, b1a, b2a, h1, h2);
  } else {
    k_stats<<<Bn, 256, 0, stream>>>(x, mask, mu, rinv, cnt);
    k_gemm1<<<dim3(8,32,2), 256, 0, stream>>>(x, cnt, mu, rinv,
        ln1_g, ln1_b, w1a, b1a, ln2_g, ln2_b, w2a, b2a, h1, h2);
  }
  k_gemm2<<<dim3(2,32,2), 256, 0, stream>>>(h1, h2, w1b, b1b, w2b, b2b, F_H, F_G, muF);
  k_covpart<<<dim3(32,3), 256, 0, stream>>>(F_H, F_G, covPart);
  k_sigma<<<dim3(64,3), 256, 0, stream>>>(covPart, muF, Sigma);
  k_nsprep<<<2, 256, 0, stream>>>(Sigma, nsY0, nsZ0, cval);

  float* Ycur = nsY0; float* Zcur = nsZ0; float* Yalt = nsY1; float* Zalt = nsZ1;
  for (int it=0; it<NS_ITERS; ++it){
    k_ns1b<<<dim3(4,4,2), 256, 0, stream>>>(Ycur, Zcur, nsT);
    k_ns2b<<<dim3(4,8,2), 256, 0, stream>>>(Ycur, Zcur, nsT, Yalt, Zalt);
    float* ty_ = Ycur; Ycur = Yalt; Yalt = ty_;
    float* tz_ = Zcur; Zcur = Zalt; Zalt = tz_;
  }

  k_mm<<<4, 256, 0, stream>>>(Zcur, Sigma + 2*16384, tmpM, cval, 0, nullptr);
  k_mm<<<4, 256, 0, stream>>>(tmpM, Zcur + 16384, Tmat, cval, 1, out + Bn);
  k_final3<<<1, 1024, 0, stream>>>(Tmat, out);
}

// Round 15
// 825.584 us; speedup vs baseline: 1.0361x; 1.0361x over previous
//
#include <hip/hip_runtime.h>
#include <math.h>
#include <stdint.h>

#define Bn 4096
#define Mn 16
#define Dn 1024
#define FLATn 16384
#define HIDn 512
#define OUTn 128
#define NS_ITERS 14
#define PB 16
#define SSI 16

typedef __attribute__((ext_vector_type(8))) short short8;
typedef __attribute__((ext_vector_type(4))) float f32x4;

__device__ __forceinline__ void wsync(){
  asm volatile("" ::: "memory");
  __builtin_amdgcn_wave_barrier();
  asm volatile("" ::: "memory");
}

// pack 8 fp32 -> bf16 (RNE)
__device__ __forceinline__ void pack8hi(const float* sv, uint4& hv){
  uint32_t h[8];
  #pragma unroll
  for (int j=0;j<8;j++){
    uint32_t u = __float_as_uint(sv[j]);
    uint32_t th = u + 0x7FFFu + ((u>>16)&1u);
    h[j] = th>>16;
  }
  hv = make_uint4(h[0]|(h[1]<<16), h[2]|(h[3]<<16), h[4]|(h[5]<<16), h[6]|(h[7]<<16));
}

// ---------------- per-sample LayerNorm stats (standalone, for fallback) ----------------
__global__ __launch_bounds__(256) void k_stats(const float* __restrict__ x,
                                               const int* __restrict__ mask,
                                               float* __restrict__ mu,
                                               float* __restrict__ rinv,
                                               int* __restrict__ cnt) {
  int b = blockIdx.x;
  int t = threadIdx.x;
  __shared__ int s_m[Mn];
  __shared__ float red[16];
  if (t < Mn) s_m[t] = mask[b*Mn + t];
  __syncthreads();
  int c = 0;
  #pragma unroll
  for (int m=0;m<Mn;m++) c += s_m[m];
  const float4* xb = (const float4*)(x + (size_t)b*FLATn);
  float sum=0.f, sq=0.f;
  for (int i=t;i<FLATn/4;i+=256){
    int m = (i>>8);
    if (s_m[m]) {
      float4 v = xb[i];
      sum += v.x+v.y+v.z+v.w;
      sq  += v.x*v.x+v.y*v.y+v.z*v.z+v.w*v.w;
    }
  }
  for (int off=32;off>0;off>>=1){ sum += __shfl_down(sum,off); sq += __shfl_down(sq,off); }
  int wv = t>>6;
  if ((t&63)==0){ red[wv]=sum; red[wv+8]=sq; }
  __syncthreads();
  if (t==0){
    float S=red[0]+red[1]+red[2]+red[3];
    float Q=red[8]+red[9]+red[10]+red[11];
    float m_ = S/(float)FLATn;
    float v_ = Q/(float)FLATn - m_*m_;
    mu[b]=m_;
    rinv[b]=rsqrtf(v_+1e-5f);
    cnt[b]=c;
  }
}

// ================= FAST PATH (MFMA) =================

// fused: blocks [0,4096) = LN stats; blocks [4096,12288) = W conversion (bf16 hi only) + bias fold
__global__ __launch_bounds__(256) void k_pre(const float* __restrict__ x,
                                             const int* __restrict__ mask,
                                             float* __restrict__ mu,
                                             float* __restrict__ rinv,
                                             int* __restrict__ cnt,
                                             const float* __restrict__ w1,
                                             const float* __restrict__ w2,
                                             const float* __restrict__ g1,
                                             const float* __restrict__ g2,
                                             const float* __restrict__ be1,
                                             const float* __restrict__ be2,
                                             ushort* __restrict__ W16,
                                             float* __restrict__ biasP){
  __shared__ int s_m[Mn];
  __shared__ float red[16];
  __shared__ float sm[256];
  const int t = threadIdx.x;
  if (blockIdx.x < 4096){
    int b = blockIdx.x;
    if (t < Mn) s_m[t] = mask[b*Mn + t];
    __syncthreads();
    int c = 0;
    #pragma unroll
    for (int m=0;m<Mn;m++) c += s_m[m];
    const float4* xb = (const float4*)(x + (size_t)b*FLATn);
    float sum=0.f, sq=0.f;
    for (int i=t;i<FLATn/4;i+=256){
      int m = (i>>8);
      if (s_m[m]) {
        float4 v = xb[i];
        sum += v.x+v.y+v.z+v.w;
        sq  += v.x*v.x+v.y*v.y+v.z*v.z+v.w*v.w;
      }
    }
    for (int off=32;off>0;off>>=1){ sum += __shfl_down(sum,off); sq += __shfl_down(sq,off); }
    int wv = t>>6;
    if ((t&63)==0){ red[wv]=sum; red[wv+8]=sq; }
    __syncthreads();
    if (t==0){
      float S=red[0]+red[1]+red[2]+red[3];
      float Q=red[8]+red[9]+red[10]+red[11];
      float m_ = S/(float)FLATn;
      float v_ = Q/(float)FLATn - m_*m_;
      mu[b]=m_;
      rinv[b]=rsqrtf(v_+1e-5f);
      cnt[b]=c;
    }
  } else {
    const size_t TE = (size_t)HIDn*FLATn;
    const int idx2 = blockIdx.x - 4096;
    const int tower = idx2 >> 12;
    const int bxw = idx2 & 4095;
    const float* w = tower? w2 : w1;
    const float* g = tower? g2 : g1;
    const float* be = tower? be2 : be1;
    size_t idx = ((size_t)bxw*256 + t)*8;
    const int k = (int)(idx & (FLATn-1));
    float4 w0 = *(const float4*)(w + idx);
    float4 w1v = *(const float4*)(w + idx + 4);
    float4 g0 = *(const float4*)(g + k);
    float4 g1v = *(const float4*)(g + k + 4);
    float4 e0 = *(const float4*)(be + k);
    float4 e1v = *(const float4*)(be + k + 4);
    float a[8] = {w0.x*g0.x, w0.y*g0.y, w0.z*g0.z, w0.w*g0.w,
                  w1v.x*g1v.x, w1v.y*g1v.y, w1v.z*g1v.z, w1v.w*g1v.w};
    uint4 hv;
    pack8hi(a, hv);
    *(uint4*)(W16 + (size_t)tower*TE + idx) = hv;
    float s = w0.x*e0.x + w0.y*e0.y + w0.z*e0.z + w0.w*e0.w
            + w1v.x*e1v.x + w1v.y*e1v.y + w1v.z*e1v.z + w1v.w*e1v.w;
    sm[t] = s; __syncthreads();
    for (int off=128; off>0; off>>=1){
      if (t < off) sm[t] += sm[t+off];
      __syncthreads();
    }
    if (t==0){
      const int o = (int)(idx >> 14);
      atomicAdd(&biasP[tower*HIDn + o], sm[0]);
    }
  }
}

__device__ __forceinline__ void glds16(const void* g, void* l){
  __builtin_amdgcn_global_load_lds((const __attribute__((address_space(1))) uint32_t*)g,
                                   (__attribute__((address_space(3))) uint32_t*)l, 16, 0, 0);
}

// MFMA GEMM (BM=128, BN=512, BK=32, 8 waves 2m x 4n), A+B double-buffered, 80KB LDS,
// single barrier per K-step. Pure bf16 (1-term): a*w ~= ah*wh; err ~1.6e-3 rel.
// [R7 schedule otherwise] 256 blocks: bid&7 = tower*4+kc (XCD-affine), bid>>3 = mi
// [R13 known-good: 284us, absmax 4.9e-4]
__global__ __launch_bounds__(512) void k_gemm1m(
    const float* __restrict__ x, const int* __restrict__ cnt,
    const float* __restrict__ mu, const float* __restrict__ rinv,
    const ushort* __restrict__ W16,
    float* __restrict__ hp){
  __shared__ uint4 A_lds[2][8][64];         // (buf, rb, lane) 16KB
  __shared__ uint4 B_lds[2][32][64];        // (buf, cb, lane) 64KB
  const int t = threadIdx.x;
  const int lane = t & 63;
  const int wid = t >> 6;
  const int wm = wid >> 2, wn = wid & 3;

  const int bid = blockIdx.x;
  const int kc = bid & 3;
  const int tower = (bid >> 2) & 1;
  const int mi = bid >> 3;
  const int b0 = mi*128;
  const size_t TE = (size_t)HIDn*FLATn;
  const ushort* Wb = W16 + (size_t)tower*TE;

  const int r = t>>2, seg = t&3;
  const int brow = b0 + r;
  const int cbr = cnt[brow];
  const float mur = mu[brow];
  const float rir = rinv[brow];
  const float* xrow = x + (size_t)brow*FLATn;
  const int rb_s = r>>4;
  const int lane_s = (r&15) + 16*seg;

  f32x4 acc[4][8];
  #pragma unroll
  for (int i=0;i<4;i++)
    #pragma unroll
    for (int j=0;j<8;j++)
      acc[i][j] = (f32x4){0.f,0.f,0.f,0.f};

  auto loadA = [&](int kt, float* dst){
    const int k0 = kc*4096 + kt*32;
    const int m = k0 >> 10;
    const int d0 = (k0 & 1023) + seg*8;
    const bool valid = m < cbr;
    int sm_ = tower ? (cbr-1-m) : m;
    if (!valid) sm_ = 0;
    const float* src = xrow + sm_*Dn + d0;
    float4 v0 = *(const float4*)(src);
    float4 v1 = *(const float4*)(src+4);
    float vv[8] = {v0.x,v0.y,v0.z,v0.w,v1.x,v1.y,v1.z,v1.w};
    #pragma unroll
    for (int j=0;j<8;j++){
      float a = valid ? vv[j] : 0.f;
      dst[j] = (a - mur)*rir;
    }
  };

  auto writeA = [&](const float* sv, int buf){
    uint4 hv;
    pack8hi(sv, hv);
    A_lds[buf][rb_s][lane_s] = hv;
  };

  auto stageB = [&](int kt, int buf){
    const int k0 = kc*4096 + kt*32;
    const int col_l = lane & 15;
    const int kk_l = k0 + (lane>>4)*8;
    #pragma unroll
    for (int q=0;q<4;q++){
      int cb = wid*4 + q;         // 0..31
      const ushort* src = Wb + (size_t)(cb*16 + col_l)*FLATn + kk_l;
      glds16((const void*)src, (void*)&B_lds[buf][cb][0]);
    }
  };

  auto compute = [&](int buf){
    short8 ah[4];
    #pragma unroll
    for (int mf=0; mf<4; ++mf)
      ah[mf] = *(const short8*)&A_lds[buf][wm*4+mf][lane];
    #pragma unroll
    for (int nf=0; nf<8; ++nf){
      short8 bh = *(const short8*)&B_lds[buf][wn*8+nf][lane];
      #pragma unroll
      for (int mf=0; mf<4; ++mf)
        acc[mf][nf] = __builtin_amdgcn_mfma_f32_16x16x32_bf16(ah[mf], bh, acc[mf][nf], 0, 0, 0);
    }
  };

  float av[8], av2[8];
  loadA(0, av);
  writeA(av, 0);
  stageB(0, 0);
  loadA(1, av);
  __syncthreads();

  #pragma unroll 1
  for (int kt=0; kt<128; ++kt){
    const int cur = kt & 1;
    if (kt < 127){
      stageB(kt+1, cur^1);
      writeA(av, cur^1);
      if (kt < 126) loadA(kt+2, av2);
    }
    compute(cur);
    __syncthreads();
    if (kt < 126){
      #pragma unroll
      for (int j=0;j<8;j++) av[j]=av2[j];
    }
  }

  float* outp = hp + (size_t)(tower*4 + kc)*Bn*HIDn;
  #pragma unroll
  for (int mf=0; mf<4; ++mf){
    #pragma unroll
    for (int nf=0; nf<8; ++nf){
      int col = wn*128 + nf*16 + (lane&15);
      int rbase = b0 + wm*64 + mf*16 + ((lane>>4)<<2);
      #pragma unroll
      for (int rg=0; rg<4; ++rg)
        outp[(size_t)(rbase+rg)*HIDn + col] = acc[mf][nf][rg];
    }
  }
}

__global__ __launch_bounds__(256) void k_fix(const float* __restrict__ hp,
                                             const float* __restrict__ biasP,
                                             const float* __restrict__ ba1,
                                             const float* __restrict__ ba2,
                                             float* __restrict__ h1,
                                             float* __restrict__ h2){
  const int tower = blockIdx.y;
  size_t e = ((size_t)blockIdx.x*256 + threadIdx.x)*4;
  const size_t TS = (size_t)Bn*HIDn;
  const float* base = hp + (size_t)tower*4*TS;
  float4 s0 = *(const float4*)(base + e);
  float4 s1 = *(const float4*)(base + TS + e);
  float4 s2 = *(const float4*)(base + 2*TS + e);
  float4 s3 = *(const float4*)(base + 3*TS + e);
  int col = (int)(e & (HIDn-1));
  float4 bp = *(const float4*)(biasP + tower*HIDn + col);
  const float* ba = tower? ba2 : ba1;
  float4 bav = *(const float4*)(ba + col);
  float4 o;
  o.x = fmaxf(s0.x+s1.x+s2.x+s3.x+bp.x+bav.x, 0.f);
  o.y = fmaxf(s0.y+s1.y+s2.y+s3.y+bp.y+bav.y, 0.f);
  o.z = fmaxf(s0.z+s1.z+s2.z+s3.z+bp.z+bav.z, 0.f);
  o.w = fmaxf(s0.w+s1.w+s2.w+s3.w+bp.w+bav.w, 0.f);
  float* h = tower? h2 : h1;
  *(float4*)(h + e) = o;
}

// ================= FALLBACK big GEMM (fp32 VALU) =================
__global__ __launch_bounds__(256) void k_gemm1(
    const float* __restrict__ x, const int* __restrict__ cnt,
    const float* __restrict__ mu, const float* __restrict__ rinv,
    const float* __restrict__ g1, const float* __restrict__ be1,
    const float* __restrict__ w1, const float* __restrict__ bias1,
    const float* __restrict__ g2, const float* __restrict__ be2,
    const float* __restrict__ w2, const float* __restrict__ bias2,
    float* __restrict__ h1, float* __restrict__ h2) {
  const int tower = blockIdx.z;
  const float* g   = tower ? g2 : g1;
  const float* be  = tower ? be2 : be1;
  const float* w   = tower ? w2 : w1;
  const float* bia = tower ? bias2 : bias1;
  float* hout      = tower ? h2 : h1;

  __shared__ float As[32][128];
  __shared__ float Bs[32][64];

  const int t  = threadIdx.x;
  const int b0 = blockIdx.y * 128;
  const int o0 = blockIdx.x * 64;

  const int ar = t & 127;
  const int ah = t >> 7;
  const int brow = b0 + ar;
  const int cb = cnt[brow];
  const float mub = mu[brow];
  const float rb  = rinv[brow];
  const float* xrow = x + (size_t)brow * FLATn;

  const int bc = t & 63;
  const int bp = t >> 6;
  const float* wrow = w + (size_t)(o0 + bc) * FLATn;

  const int tx = t & 15, ty = t >> 4;
  const int c0 = tx*4, r0 = ty*8;

  float acc[8][4];
  #pragma unroll
  for (int i=0;i<8;i++){
    #pragma unroll
    for (int j=0;j<4;j++) acc[i][j]=0.f;
  }

  for (int kt=0; kt<FLATn/32; ++kt){
    const int k0 = kt*32;
    const int m  = k0 >> 10;
    const int d0 = k0 & 1023;
    {
      const int sm_ = tower ? (cb-1-m) : m;
      const bool valid = (m < cb);
      const float* src = xrow + sm_*Dn + d0 + ah*16;
      const float* gk  = g  + k0 + ah*16;
      const float* bk  = be + k0 + ah*16;
      #pragma unroll
      for (int q=0;q<4;q++){
        float4 v = valid ? *(const float4*)(src + q*4) : make_float4(0.f,0.f,0.f,0.f);
        float4 gg = *(const float4*)(gk + q*4);
        float4 bb = *(const float4*)(bk + q*4);
        int kk = ah*16 + q*4;
        As[kk+0][ar] = (v.x - mub)*rb*gg.x + bb.x;
        As[kk+1][ar] = (v.y - mub)*rb*gg.y + bb.y;
        As[kk+2][ar] = (v.z - mub)*rb*gg.z + bb.z;
        As[kk+3][ar] = (v.w - mub)*rb*gg.w + bb.w;
      }
    }
    {
      const float* srcw = wrow + k0 + bp*8;
      #pragma unroll
      for (int q=0;q<2;q++){
        float4 v = *(const float4*)(srcw + q*4);
        int kk = bp*8 + q*4;
        Bs[kk+0][bc]=v.x; Bs[kk+1][bc]=v.y; Bs[kk+2][bc]=v.z; Bs[kk+3][bc]=v.w;
      }
    }
    __syncthreads();
    #pragma unroll
    for (int kk=0;kk<32;kk++){
      float a[8], bb4[4];
      *(float4*)&a[0] = *(const float4*)&As[kk][r0];
      *(float4*)&a[4] = *(const float4*)&As[kk][r0+4];
      *(float4*)&bb4[0] = *(const float4*)&Bs[kk][c0];
      #pragma unroll
      for (int i=0;i<8;i++){
        #pragma unroll
        for (int j=0;j<4;j++) acc[i][j] += a[i]*bb4[j];
      }
    }
    __syncthreads();
  }
  float4 bv = *(const float4*)(bia + o0 + c0);
  #pragma unroll
  for (int i=0;i<8;i++){
    float4 ov;
    ov.x = fmaxf(acc[i][0]+bv.x, 0.f);
    ov.y = fmaxf(acc[i][1]+bv.y, 0.f);
    ov.z = fmaxf(acc[i][2]+bv.z, 0.f);
    ov.w = fmaxf(acc[i][3]+bv.w, 0.f);
    *(float4*)(hout + (size_t)(b0+r0+i)*HIDn + o0 + c0) = ov;
  }
}

// ---------------- second linear (+ fused batch-mean accumulation) ----------------
__global__ __launch_bounds__(256) void k_gemm2(
    const float* __restrict__ h1, const float* __restrict__ h2,
    const float* __restrict__ wb1, const float* __restrict__ bb1,
    const float* __restrict__ wb2, const float* __restrict__ bb2,
    float* __restrict__ F_H, float* __restrict__ F_G,
    float* __restrict__ muF) {
  const int tower = blockIdx.z;
  const float* A   = tower ? h2 : h1;
  const float* w   = tower ? wb2 : wb1;
  const float* bia = tower ? bb2 : bb1;
  float* F         = tower ? F_G : F_H;

  __shared__ float As[32][128];
  __shared__ float Bs[32][64];

  const int t  = threadIdx.x;
  const int b0 = blockIdx.y * 128;
  const int o0 = blockIdx.x * 64;

  const int ar = t & 127;
  const int ah = t >> 7;
  const float* arow = A + (size_t)(b0+ar)*HIDn;
  const int bc = t & 63;
  const int bp = t >> 6;
  const float* wrow = w + (size_t)(o0+bc)*HIDn;

  const int tx = t & 15, ty = t >> 4;
  const int c0 = tx*4, r0 = ty*8;

  float acc[8][4];
  #pragma unroll
  for (int i=0;i<8;i++){
    #pragma unroll
    for (int j=0;j<4;j++) acc[i][j]=0.f;
  }

  for (int kt=0; kt<HIDn/32; ++kt){
    const int k0 = kt*32;
    #pragma unroll
    for (int q=0;q<4;q++){
      float4 v = *(const float4*)(arow + k0 + ah*16 + q*4);
      int kk = ah*16+q*4;
      As[kk+0][ar]=v.x; As[kk+1][ar]=v.y; As[kk+2][ar]=v.z; As[kk+3][ar]=v.w;
    }
    #pragma unroll
    for (int q=0;q<2;q++){
      float4 v = *(const float4*)(wrow + k0 + bp*8 + q*4);
      int kk = bp*8+q*4;
      Bs[kk+0][bc]=v.x; Bs[kk+1][bc]=v.y; Bs[kk+2][bc]=v.z; Bs[kk+3][bc]=v.w;
    }
    __syncthreads();
    #pragma unroll
    for (int kk=0;kk<32;kk++){
      float a[8], bb4[4];
      *(float4*)&a[0] = *(const float4*)&As[kk][r0];
      *(float4*)&a[4] = *(const float4*)&As[kk][r0+4];
      *(float4*)&bb4[0] = *(const float4*)&Bs[kk][c0];
      #pragma unroll
      for (int i=0;i<8;i++){
        #pragma unroll
        for (int j=0;j<4;j++) acc[i][j] += a[i]*bb4[j];
      }
    }
    __syncthreads();
  }
  float4 bv = *(const float4*)(bia + o0 + c0);
  float cs[4];
  #pragma unroll
  for (int j=0;j<4;j++) cs[j]=0.f;
  #pragma unroll
  for (int i=0;i<8;i++){
    float4 ov;
    ov.x = acc[i][0]+bv.x;
    ov.y = acc[i][1]+bv.y;
    ov.z = acc[i][2]+bv.z;
    ov.w = acc[i][3]+bv.w;
    cs[0]+=ov.x; cs[1]+=ov.y; cs[2]+=ov.z; cs[3]+=ov.w;
    *(float4*)(F + (size_t)(b0+r0+i)*OUTn + o0 + c0) = ov;
  }
  float* red = &As[0][0];
  #pragma unroll
  for (int j=0;j<4;j++) red[ty*64 + c0 + j] = cs[j];
  __syncthreads();
  if (ty==0){
    #pragma unroll
    for (int j=0;j<4;j++){
      float tot=0.f;
      for (int q=0;q<16;q++) tot += red[q*64 + c0 + j];
      atomicAdd(&muF[tower*OUTn + o0 + c0 + j], tot);
    }
  }
}

// ---------------- covariance partials ----------------
__global__ __launch_bounds__(256) void k_covpart(const float* __restrict__ F_H,
                                                 const float* __restrict__ F_G,
                                                 float* __restrict__ covPart){
  const int s  = blockIdx.y;
  const int kc = blockIdx.x;
  const float* F1 = (s==1)? F_G : F_H;
  const float* F2 = (s==0)? F_H : F_G;
  __shared__ float A1[32][128], A2[32][128];
  const int t = threadIdx.x;
  const int tx = t & 15, ty = t >> 4;
  const int i0 = ty*8, j0 = tx*8;
  float acc[8][8];
  #pragma unroll
  for (int i=0;i<8;i++){
    #pragma unroll
    for (int j=0;j<8;j++) acc[i][j]=0.f;
  }
  const int kr = t >> 3;
  const int kp = (t & 7) * 16;
  for (int sub=0; sub<4; ++sub){
    const int kbase = kc*128 + sub*32;
    const float* p1 = F1 + (size_t)(kbase + kr)*OUTn + kp;
    const float* p2 = F2 + (size_t)(kbase + kr)*OUTn + kp;
    #pragma unroll
    for (int q=0;q<4;q++){
      *(float4*)&A1[kr][kp + q*4] = *(const float4*)(p1 + q*4);
      *(float4*)&A2[kr][kp + q*4] = *(const float4*)(p2 + q*4);
    }
    __syncthreads();
    #pragma unroll
    for (int kk=0;kk<32;kk++){
      float a[8], b[8];
      *(float4*)&a[0] = *(const float4*)&A1[kk][i0];
      *(float4*)&a[4] = *(const float4*)&A1[kk][i0+4];
      *(float4*)&b[0] = *(const float4*)&A2[kk][j0];
      *(float4*)&b[4] = *(const float4*)&A2[kk][j0+4];
      #pragma unroll
      for (int i=0;i<8;i++){
        #pragma unroll
        for (int j=0;j<8;j++) acc[i][j] += a[i]*b[j];
      }
    }
    __syncthreads();
  }
  float* outp = covPart + (size_t)(s*32 + kc)*OUTn*OUTn;
  #pragma unroll
  for (int i=0;i<8;i++){
    #pragma unroll
    for (int j=0;j<8;j+=4){
      *(float4*)(outp + (size_t)(i0+i)*OUTn + j0 + j) =
          make_float4(acc[i][j],acc[i][j+1],acc[i][j+2],acc[i][j+3]);
    }
  }
}

// muF holds column SUMS (not means)
__global__ __launch_bounds__(256) void k_sigma(const float* __restrict__ covPart,
                                               const float* __restrict__ muF,
                                               float* __restrict__ Sigma){
  const int s = blockIdx.y;
  const int e = blockIdx.x*256 + threadIdx.x;
  const int i = e >> 7, j = e & 127;
  float acc = 0.f;
  for (int c=0;c<32;c++) acc += covPart[(size_t)(s*32+c)*16384 + e];
  const float* mu1 = muF + ((s==1)? 128 : 0);
  const float* mu2 = muF + ((s==0)? 0 : 128);
  float v = (acc - mu1[i]*mu2[j]*(1.0f/(float)Bn)) * (1.0f/(float)(Bn-1));
  if (s < 2 && i==j) v += 1e-4f;
  Sigma[(size_t)s*16384 + e] = v;
}

// ---------------- Newton-Schulz prep ----------------
__global__ __launch_bounds__(256) void k_nsprep(const float* __restrict__ Sigma,
                                                float* __restrict__ Yb,
                                                float* __restrict__ Zb,
                                                float* __restrict__ cval){
  const int s = blockIdx.x;
  const float* A = Sigma + (size_t)s*16384;
  __shared__ float As[16384];
  __shared__ float v[128], w[128];
  __shared__ float sh[4];
  const int t = threadIdx.x;
  for (int i=t;i<16384;i+=256) As[i]=A[i];
  if (t<128) v[t]=1.f;
  __syncthreads();
  float lam = 1.f;
  for (int it=0; it<12; ++it){
    const int i = t>>1, hf = t&1;
    float ss=0.f;
    const float* Ai = &As[i*128];
    for (int q=hf*64;q<hf*64+64;q++) ss += Ai[q]*v[q];
    ss += __shfl_xor(ss,1);
    if (hf==0) w[i]=ss;
    __syncthreads();
    if (t==0){
      float n2=0.f;
      for (int q2=0;q2<128;q2++) n2 += w[q2]*w[q2];
      sh[0] = sqrtf(n2);
    }
    __syncthreads();
    const float nrm = sh[0];
    lam = nrm;
    if (t<128) v[t] = w[t] / fmaxf(nrm, 1e-30f);
    __syncthreads();
  }
  const float c = 1.05f*lam + 1e-20f;
  const float invc = 1.f/c;
  float* Yp = Yb + (size_t)s*16384;
  float* Zp = Zb + (size_t)s*16384;
  for (int i=t;i<16384;i+=256){
    Yp[i] = As[i]*invc;
    Zp[i] = ((i>>7)==(i&127)) ? 1.f : 0.f;
  }
  if (t==0) cval[s]=c;
}

// ---------------- NS retiled: 32x32 C-tiles ----------------
__global__ __launch_bounds__(256) void k_ns1b(const float* __restrict__ Yb,
                                              const float* __restrict__ Zb,
                                              float* __restrict__ Tb){
  const int s = blockIdx.z;
  const float* Y = Yb + (size_t)s*16384;
  const float* Z = Zb + (size_t)s*16384;
  float* T = Tb + (size_t)s*16384;
  const int r0 = blockIdx.y*32, c0 = blockIdx.x*32;
  __shared__ float As[32][132];
  __shared__ float Bs[128][32];
  const int t = threadIdx.x;
  #pragma unroll
  for (int q=0;q<4;q++){
    int i = q*1024 + t*4;
    int row = i>>7, colx = i&127;
    *(float4*)&As[row][colx] = *(const float4*)(Z + (size_t)(r0+row)*128 + colx);
    int k = i>>5, cc = i&31;
    *(float4*)&Bs[k][cc] = *(const float4*)(Y + (size_t)k*128 + c0 + cc);
  }
  __syncthreads();
  const int r = t>>3, cg = t&7;
  float acc[4] = {0.f,0.f,0.f,0.f};
  #pragma unroll
  for (int k4=0;k4<32;k4++){
    float4 a4 = *(const float4*)&As[r][k4*4];
    float aa[4] = {a4.x,a4.y,a4.z,a4.w};
    #pragma unroll
    for (int kk=0;kk<4;kk++){
      float4 b = *(const float4*)&Bs[k4*4+kk][cg*4];
      acc[0] += aa[kk]*b.x; acc[1] += aa[kk]*b.y;
      acc[2] += aa[kk]*b.z; acc[3] += aa[kk]*b.w;
    }
  }
  const int gr = r0 + r;
  const int gc = c0 + cg*4;
  float4 o;
  o.x = ((gr==gc+0)?3.f:0.f) - acc[0];
  o.y = ((gr==gc+1)?3.f:0.f) - acc[1];
  o.z = ((gr==gc+2)?3.f:0.f) - acc[2];
  o.w = ((gr==gc+3)?3.f:0.f) - acc[3];
  *(float4*)(T + (size_t)gr*128 + gc) = o;
}

__global__ __launch_bounds__(256) void k_ns2b(const float* __restrict__ Yb,
                                              const float* __restrict__ Zb,
                                              const float* __restrict__ Tb,
                                              float* __restrict__ Ynb,
                                              float* __restrict__ Znb){
  const int s = blockIdx.z;
  const int which = blockIdx.y >> 2;
  const int r0 = (blockIdx.y & 3)*32, c0 = blockIdx.x*32;
  const float* Am = which ? (Tb + (size_t)s*16384) : (Yb + (size_t)s*16384);
  const float* Bm = which ? (Zb + (size_t)s*16384) : (Tb + (size_t)s*16384);
  float* C = which ? (Znb + (size_t)s*16384) : (Ynb + (size_t)s*16384);
  __shared__ float As[32][132];
  __shared__ float Bs[128][32];
  const int t = threadIdx.x;
  #pragma unroll
  for (int q=0;q<4;q++){
    int i = q*1024 + t*4;
    int row = i>>7, colx = i&127;
    *(float4*)&As[row][colx] = *(const float4*)(Am + (size_t)(r0+row)*128 + colx);
    int k = i>>5, cc = i&31;
    *(float4*)&Bs[k][cc] = *(const float4*)(Bm + (size_t)k*128 + c0 + cc);
  }
  __syncthreads();
  const int r = t>>3, cg = t&7;
  float acc[4] = {0.f,0.f,0.f,0.f};
  #pragma unroll
  for (int k4=0;k4<32;k4++){
    float4 a4 = *(const float4*)&As[r][k4*4];
    float aa[4] = {a4.x,a4.y,a4.z,a4.w};
    #pragma unroll
    for (int kk=0;kk<4;kk++){
      float4 b = *(const float4*)&Bs[k4*4+kk][cg*4];
      acc[0] += aa[kk]*b.x; acc[1] += aa[kk]*b.y;
      acc[2] += aa[kk]*b.z; acc[3] += aa[kk]*b.w;
    }
  }
  float4 o = make_float4(0.5f*acc[0], 0.5f*acc[1], 0.5f*acc[2], 0.5f*acc[3]);
  *(float4*)(C + (size_t)(r0+r)*128 + c0 + cg*4) = o;
}

__device__ __forceinline__ void mm_acc16(const float* __restrict__ Arow,
                                         const float* __restrict__ Bs,
                                         int c0, float* acc){
  for (int k4=0;k4<128;k4+=4){
    float4 av = *(const float4*)(Arow + k4);
    float aa[4] = {av.x, av.y, av.z, av.w};
    #pragma unroll
    for (int kk=0;kk<4;kk++){
      const float a = aa[kk];
      const float* bp = &Bs[(k4+kk)*128 + c0];
      const float4 b0 = *(const float4*)(bp);
      const float4 b1 = *(const float4*)(bp+4);
      const float4 b2 = *(const float4*)(bp+8);
      const float4 b3 = *(const float4*)(bp+12);
      acc[0]+=a*b0.x;  acc[1]+=a*b0.y;  acc[2]+=a*b0.z;  acc[3]+=a*b0.w;
      acc[4]+=a*b1.x;  acc[5]+=a*b1.y;  acc[6]+=a*b1.z;  acc[7]+=a*b1.w;
      acc[8]+=a*b2.x;  acc[9]+=a*b2.y;  acc[10]+=a*b2.z; acc[11]+=a*b2.w;
      acc[12]+=a*b3.x; acc[13]+=a*b3.y; acc[14]+=a*b3.z; acc[15]+=a*b3.w;
    }
  }
}

__global__ __launch_bounds__(256) void k_mm(const float* __restrict__ Am,
                                            const float* __restrict__ Bm,
                                            float* __restrict__ C,
                                            const float* __restrict__ cval,
                                            const int useScale,
                                            float* __restrict__ out2){
  __shared__ float Bs[16384];
  const int t = threadIdx.x;
  for (int i=t;i<16384;i+=256) Bs[i]=Bm[i];
  __syncthreads();
  const int r = blockIdx.x*32 + (t>>3);
  const int c0 = (t&7)*16;
  float acc[16];
  #pragma unroll
  for (int j=0;j<16;j++) acc[j]=0.f;
  mm_acc16(Am + (size_t)r*128, Bs, c0, acc);
  const float scale = useScale ? rsqrtf(cval[0]*cval[1]) : 1.f;
  float* Cr = C + (size_t)r*128 + c0;
  #pragma unroll
  for (int j=0;j<16;j++) Cr[j] = acc[j]*scale;
  if (out2 != nullptr){
    float* Or = out2 + (size_t)r*128 + c0;
    #pragma unroll
    for (int j=0;j<16;j++) Or[j] = acc[j]*scale;
  }
}

// ---------------- fused E=T^T T + top-10 sqrt-eigenvalues via subspace iteration ----------------
__device__ __forceinline__ void pairpq(int k, int rr, int& p, int& q){
  if (k==0){ p = 15; q = rr % 15; }
  else { p = (rr + k) % 15; q = (rr + 15 - k) % 15; }
}

__global__ __launch_bounds__(1024) void k_final3(const float* __restrict__ Tmat,
                                                 float* __restrict__ outp){
  __shared__ float Es[128*132];
  __shared__ float Tt[128*132];
  __shared__ float Vt[PB*132];
  __shared__ float Wt[PB*132];
  __shared__ float GP[PB*PB*4];
  __shared__ float Gs[PB*17];
  __shared__ float Ls[PB*17];
  __shared__ float rLs[PB];
  __shared__ float Ms[PB*17];
  __shared__ float cs_[8], sn_[8];
  __shared__ float scoreSh;

  const int t = threadIdx.x;
  for (int i=t;i<16384;i+=1024)
    Tt[(i>>7)*132 + (i&127)] = Tmat[i];
  for (int i=t;i<PB*128;i+=1024){
    uint32_t u = (uint32_t)i*2654435761u + 0x9E3779B9u;
    u ^= u>>16; u *= 0x85EBCA6Bu; u ^= u>>13;
    float rv = ((float)(u & 0xFFFF) - 32768.0f) * (1.0f/32768.0f);
    Vt[(i>>7)*132 + (i&127)] = rv;
  }
  __syncthreads();

  // E = T^T @ T
  {
    const int ei = t>>3, ej0 = (t&7)*16;
    float ea[16];
    #pragma unroll
    for (int j=0;j<16;j++) ea[j]=0.f;
    for (int k=0;k<128;k++){
      float a = Tt[k*132 + ei];
      #pragma unroll
      for (int j=0;j<16;j+=4){
        float4 b = *(const float4*)&Tt[k*132 + ej0 + j];
        ea[j]+=a*b.x; ea[j+1]+=a*b.y; ea[j+2]+=a*b.z; ea[j+3]+=a*b.w;
      }
    }
    #pragma unroll
    for (int j=0;j<16;j++) Es[ei*132 + ej0 + j] = ea[j];
  }
  __syncthreads();

  const int c  = t & 15;
  const int r0 = t >> 4;
  const int gi = t >> 6;
  const int gj = (t >> 2) & 15;
  const int gq = t & 3;

  for (int it=0; it<=SSI; ++it){
    float a0=0.f, a1=0.f;
    {
      const float* vr = &Vt[c*132];
      const float* e0 = &Es[r0*132];
      const float* e1 = &Es[(r0+64)*132];
      #pragma unroll
      for (int k4=0;k4<32;k4++){
        float4 vv = *(const float4*)(vr + k4*4);
        float4 x0 = *(const float4*)(e0 + k4*4);
        float4 x1 = *(const float4*)(e1 + k4*4);
        a0 += x0.x*vv.x + x0.y*vv.y + x0.z*vv.z + x0.w*vv.w;
        a1 += x1.x*vv.x + x1.y*vv.y + x1.z*vv.z + x1.w*vv.w;
      }
    }
    Wt[c*132 + r0] = a0;
    Wt[c*132 + r0 + 64] = a1;
    __syncthreads();

    if (it == SSI) break;

    {
      float s = 0.f;
      const float* wi = &Wt[gi*132 + gq*32];
      const float* wj = &Wt[gj*132 + gq*32];
      #pragma unroll
      for (int k4=0;k4<8;k4++){
        float4 va = *(const float4*)(wi + k4*4);
        float4 vb = *(const float4*)(wj + k4*4);
        s += va.x*vb.x + va.y*vb.y + va.z*vb.z + va.w*vb.w;
      }
      GP[(gi*16+gj)*4 + gq] = s;
    }
    __syncthreads();
    if (t < 256){
      int i = t>>4, j = t&15;
      float g = GP[(i*16+j)*4+0]+GP[(i*16+j)*4+1]+GP[(i*16+j)*4+2]+GP[(i*16+j)*4+3];
      if (i==j) g *= 1.0000012f;
      Gs[i*17+j] = g;
    }
    __syncthreads();

    if (t < 64){
      const int j = t & 15;
      float g[PB], l[PB];
      #pragma unroll
      for (int i=0;i<PB;i++) g[i] = Gs[j*17+i];
      const float g00 = Gs[0];
      const float floorv = fmaxf(1e-12f*g00, 1e-30f);
      #pragma unroll
      for (int k=0;k<PB;k++){
        float dkk = __shfl(g[k], k);
        dkk = sqrtf(fmaxf(dkk, floorv));
        float ljk = g[k] / dkk;
        l[k] = ljk;
        #pragma unroll
        for (int i2=0;i2<PB;i2++){
          if (i2 > k) g[i2] -= ljk * __shfl(ljk, i2);
        }
      }
      if (t < 16){
        #pragma unroll
        for (int k=0;k<PB;k++) Ls[j*17+k] = (k<=j)? l[k] : 0.f;
        rLs[j] = 1.f / l[j];
      }
    }
    __syncthreads();

    if (t < 128){
      const int r = t;
      float w[PB], y[PB];
      #pragma unroll
      for (int i=0;i<PB;i++) w[i] = Wt[i*132 + r];
      #pragma unroll
      for (int i=0;i<PB;i++){
        float a = w[i];
        #pragma unroll
        for (int q2=0;q2<PB;q2++){
          if (q2 < i) a -= Ls[i*17+q2] * y[q2];
        }
        y[i] = a * rLs[i];
      }
      #pragma unroll
      for (int i=0;i<PB;i++) Vt[i*132 + r] = y[i];
    }
    __syncthreads();
  }

  {
    float s = 0.f;
    const float* vi = &Vt[gi*132 + gq*32];
    const float* wj = &Wt[gj*132 + gq*32];
    #pragma unroll
    for (int k4=0;k4<8;k4++){
      float4 va = *(const float4*)(vi + k4*4);
      float4 vb = *(const float4*)(wj + k4*4);
      s += va.x*vb.x + va.y*vb.y + va.z*vb.z + va.w*vb.w;
    }
    GP[(gi*16+gj)*4 + gq] = s;
  }
  __syncthreads();
  if (t < 256){
    int i = t>>4, j = t&15;
    Gs[i*17+j] = GP[(i*16+j)*4+0]+GP[(i*16+j)*4+1]+GP[(i*16+j)*4+2]+GP[(i*16+j)*4+3];
  }
  __syncthreads();
  if (t < 256){
    int i = t>>4, j = t&15;
    Ms[i*17+j] = 0.5f*(Gs[i*17+j] + Gs[j*17+i]);
  }
  __syncthreads();

  if (t < 64){
    volatile float* M = Ms;
    const int c16 = t & 15;
    const int kk0 = t >> 4;
    for (int sweep=0; sweep<7; ++sweep){
      for (int rr=0; rr<15; ++rr){
        if (t < 8){
          int p, q; pairpq(t, rr, p, q);
          float app = M[p*17+p], aqq = M[q*17+q], apq = M[p*17+q];
          float cc=1.f, ss=0.f;
          float denom = fabsf(app)+fabsf(aqq);
          if (fabsf(apq) > 1e-12f*denom + 1e-32f){
            float tau = (aqq - app) / (2.f*apq);
            float tt = ((tau>=0.f)?1.f:-1.f) / (fabsf(tau) + sqrtf(1.f + tau*tau));
            cc = rsqrtf(1.f + tt*tt);
            ss = tt*cc;
          }
          cs_[t] = cc; sn_[t] = ss;
        }
        wsync();
        #pragma unroll
        for (int kx=0; kx<2; kx++){
          int k = kk0 + kx*4;
          int p, q; pairpq(k, rr, p, q);
          float cc = cs_[k], ss = sn_[k];
          float mp = M[p*17+c16], mq = M[q*17+c16];
          M[p*17+c16] = cc*mp - ss*mq;
          M[q*17+c16] = ss*mp + cc*mq;
        }
        wsync();
        #pragma unroll
        for (int kx=0; kx<2; kx++){
          int k = kk0 + kx*4;
          int p, q; pairpq(k, rr, p, q);
          float cc = cs_[k], ss = sn_[k];
          float mp = M[c16*17+p], mq = M[c16*17+q];
          M[c16*17+p] = cc*mp - ss*mq;
          M[c16*17+q] = ss*mp + cc*mq;
        }
        wsync();
      }
    }
    if (t < 16){
      float di = M[t*17+t];
      int cnt2 = 0;
      #pragma unroll
      for (int j=0;j<16;j++){
        float dj = M[j*17+j];
        cnt2 += (dj > di || (dj == di && j < t)) ? 1 : 0;
      }
      float qc = (cnt2 < 10) ? sqrtf(fmaxf(di, 0.f)) : 0.f;
      #pragma unroll
      for (int off=8;off>0;off>>=1) qc += __shfl_down(qc, off);
      if (t==0){
        float qv = qc * 0.1f;
        scoreSh = 1.f/(1.f+expf(-qv));
      }
    }
  }
  __syncthreads();
  const float sc = scoreSh;
  for (int i=t;i<Bn;i+=1024) outp[i] = sc;
}

extern "C" void kernel_launch(void* const* d_in, const int* in_sizes, int n_in,
                              void* d_out, int out_size, void* d_ws, size_t ws_size,
                              hipStream_t stream) {
  (void)in_sizes; (void)n_in; (void)out_size;
  const float* x     = (const float*)d_in[0];
  const int*   mask  = (const int*)d_in[1];
  const float* ln1_g = (const float*)d_in[2];
  const float* ln1_b = (const float*)d_in[3];
  const float* w1a   = (const float*)d_in[4];
  const float* b1a   = (const float*)d_in[5];
  const float* w1b   = (const float*)d_in[6];
  const float* b1b   = (const float*)d_in[7];
  const float* ln2_g = (const float*)d_in[8];
  const float* ln2_b = (const float*)d_in[9];
  const float* w2a   = (const float*)d_in[10];
  const float* b2a   = (const float*)d_in[11];
  const float* w2b   = (const float*)d_in[12];
  const float* b2b   = (const float*)d_in[13];
  float* out = (float*)d_out;

  char* ws = (char*)d_ws;
  float* mu      = (float*)(ws);
  float* rinv    = (float*)(ws + (16<<10));
  int*   cnt     = (int*)  (ws + (32<<10));
  float* muF     = (float*)(ws + (48<<10));
  float* cval    = (float*)(ws + (52<<10));
  float* biasP   = (float*)(ws + (56<<10));
  float* Sigma   = (float*)(ws + (128<<10));
  const size_t nsOff = (size_t)512<<10;
  float* nsY0 = (float*)(ws + nsOff);
  float* nsY1 = (float*)(ws + nsOff + (128<<10));
  float* nsZ0 = (float*)(ws + nsOff + (256<<10));
  float* nsZ1 = (float*)(ws + nsOff + (384<<10));
  float* nsT  = (float*)(ws + nsOff + (512<<10));
  float* tmpM = (float*)(ws + nsOff + (640<<10));
  float* Tmat = (float*)(ws + nsOff + (704<<10));
  float* F_H  = (float*)(ws + ((size_t)2<<20));
  float* F_G  = (float*)(ws + ((size_t)4<<20));
  float* h1   = (float*)(ws + ((size_t)6<<20));
  float* h2   = (float*)(ws + ((size_t)14<<20));
  float* covPart = (float*)(ws + ((size_t)6<<20));
  float*  hp  = (float*)(ws + ((size_t)24<<20));
  ushort* W16 = (ushort*)(ws + ((size_t)88<<20));

  const bool fast = ws_size >= ((size_t)153<<20);

  // zero muF (col-sum accumulators), cval, biasP
  hipMemsetAsync((void*)(ws + (48<<10)), 0, (12<<10), stream);

  if (fast){
    k_pre<<<12288, 256, 0, stream>>>(x, mask, mu, rinv, cnt,
        w1a, w2a, ln1_g, ln2_g, ln1_b, ln2_b, W16, biasP);
    k_gemm1m<<<256, 512, 0, stream>>>(x, cnt, mu, rinv, W16, hp);
    k_fix<<<dim3(2048,2), 256, 0, stream>>>(hp, biasP, b1a, b2a, h1, h2);
  } else {
    k_stats<<<Bn, 256, 0, stream>>>(x, mask, mu, rinv, cnt);
    k_gemm1<<<dim3(8,32,2), 256, 0, stream>>>(x, cnt, mu, rinv,
        ln1_g, ln1_b, w1a, b1a, ln2_g, ln2_b, w2a, b2a, h1, h2);
  }
  k_gemm2<<<dim3(2,32,2), 256, 0, stream>>>(h1, h2, w1b, b1b, w2b, b2b, F_H, F_G, muF);
  k_covpart<<<dim3(32,3), 256, 0, stream>>>(F_H, F_G, covPart);
  k_sigma<<<dim3(64,3), 256, 0, stream>>>(covPart, muF, Sigma);
  k_nsprep<<<2, 256, 0, stream>>>(Sigma, nsY0, nsZ0, cval);

  float* Ycur = nsY0; float* Zcur = nsZ0; float* Yalt = nsY1; float* Zalt = nsZ1;
  for (int it=0; it<NS_ITERS; ++it){
    k_ns1b<<<dim3(4,4,2), 256, 0, stream>>>(Ycur, Zcur, nsT);
    k_ns2b<<<dim3(4,8,2), 256, 0, stream>>>(Ycur, Zcur, nsT, Yalt, Zalt);
    float* ty_ = Ycur; Ycur = Yalt; Yalt = ty_;
    float* tz_ = Zcur; Zcur = Zalt; Zalt = tz_;
  }

  k_mm<<<4, 256, 0, stream>>>(Zcur, Sigma + 2*16384, tmpM, cval, 0, nullptr);
  k_mm<<<4, 256, 0, stream>>>(tmpM, Zcur + 16384, Tmat, cval, 1, out + Bn);
  k_final3<<<1, 1024, 0, stream>>>(Tmat, out);
}

// Round 16
// 816.765 us; speedup vs baseline: 1.0473x; 1.0108x over previous
//
#include <hip/hip_runtime.h>
#include <math.h>
#include <stdint.h>

#define Bn 4096
#define Mn 16
#define Dn 1024
#define FLATn 16384
#define HIDn 512
#define OUTn 128
#define NS_ITERS 14
#define PB 16
#define SSI 16

typedef __attribute__((ext_vector_type(8))) short short8;
typedef __attribute__((ext_vector_type(4))) float f32x4;

__device__ __forceinline__ void wsync(){
  asm volatile("" ::: "memory");
  __builtin_amdgcn_wave_barrier();
  asm volatile("" ::: "memory");
}

// pack 8 fp32 -> bf16 (RNE)
__device__ __forceinline__ void pack8hi(const float* sv, uint4& hv){
  uint32_t h[8];
  #pragma unroll
  for (int j=0;j<8;j++){
    uint32_t u = __float_as_uint(sv[j]);
    uint32_t th = u + 0x7FFFu + ((u>>16)&1u);
    h[j] = th>>16;
  }
  hv = make_uint4(h[0]|(h[1]<<16), h[2]|(h[3]<<16), h[4]|(h[5]<<16), h[6]|(h[7]<<16));
}

// ---------------- per-sample LayerNorm stats (standalone, for fallback) ----------------
__global__ __launch_bounds__(256) void k_stats(const float* __restrict__ x,
                                               const int* __restrict__ mask,
                                               float* __restrict__ mu,
                                               float* __restrict__ rinv,
                                               int* __restrict__ cnt) {
  int b = blockIdx.x;
  int t = threadIdx.x;
  __shared__ int s_m[Mn];
  __shared__ float red[16];
  if (t < Mn) s_m[t] = mask[b*Mn + t];
  __syncthreads();
  int c = 0;
  #pragma unroll
  for (int m=0;m<Mn;m++) c += s_m[m];
  const float4* xb = (const float4*)(x + (size_t)b*FLATn);
  float sum=0.f, sq=0.f;
  for (int i=t;i<FLATn/4;i+=256){
    int m = (i>>8);
    if (s_m[m]) {
      float4 v = xb[i];
      sum += v.x+v.y+v.z+v.w;
      sq  += v.x*v.x+v.y*v.y+v.z*v.z+v.w*v.w;
    }
  }
  for (int off=32;off>0;off>>=1){ sum += __shfl_down(sum,off); sq += __shfl_down(sq,off); }
  int wv = t>>6;
  if ((t&63)==0){ red[wv]=sum; red[wv+8]=sq; }
  __syncthreads();
  if (t==0){
    float S=red[0]+red[1]+red[2]+red[3];
    float Q=red[8]+red[9]+red[10]+red[11];
    float m_ = S/(float)FLATn;
    float v_ = Q/(float)FLATn - m_*m_;
    mu[b]=m_;
    rinv[b]=rsqrtf(v_+1e-5f);
    cnt[b]=c;
  }
}

// ================= FAST PATH (MFMA) =================

// fused: blocks [0,4096) = LN stats; blocks [4096,12288) = W conversion (bf16 hi only) + bias fold
__global__ __launch_bounds__(256) void k_pre(const float* __restrict__ x,
                                             const int* __restrict__ mask,
                                             float* __restrict__ mu,
                                             float* __restrict__ rinv,
                                             int* __restrict__ cnt,
                                             const float* __restrict__ w1,
                                             const float* __restrict__ w2,
                                             const float* __restrict__ g1,
                                             const float* __restrict__ g2,
                                             const float* __restrict__ be1,
                                             const float* __restrict__ be2,
                                             ushort* __restrict__ W16,
                                             float* __restrict__ biasP){
  __shared__ int s_m[Mn];
  __shared__ float red[16];
  __shared__ float sm[256];
  const int t = threadIdx.x;
  if (blockIdx.x < 4096){
    int b = blockIdx.x;
    if (t < Mn) s_m[t] = mask[b*Mn + t];
    __syncthreads();
    int c = 0;
    #pragma unroll
    for (int m=0;m<Mn;m++) c += s_m[m];
    const float4* xb = (const float4*)(x + (size_t)b*FLATn);
    float sum=0.f, sq=0.f;
    for (int i=t;i<FLATn/4;i+=256){
      int m = (i>>8);
      if (s_m[m]) {
        float4 v = xb[i];
        sum += v.x+v.y+v.z+v.w;
        sq  += v.x*v.x+v.y*v.y+v.z*v.z+v.w*v.w;
      }
    }
    for (int off=32;off>0;off>>=1){ sum += __shfl_down(sum,off); sq += __shfl_down(sq,off); }
    int wv = t>>6;
    if ((t&63)==0){ red[wv]=sum; red[wv+8]=sq; }
    __syncthreads();
    if (t==0){
      float S=red[0]+red[1]+red[2]+red[3];
      float Q=red[8]+red[9]+red[10]+red[11];
      float m_ = S/(float)FLATn;
      float v_ = Q/(float)FLATn - m_*m_;
      mu[b]=m_;
      rinv[b]=rsqrtf(v_+1e-5f);
      cnt[b]=c;
    }
  } else {
    const size_t TE = (size_t)HIDn*FLATn;
    const int idx2 = blockIdx.x - 4096;
    const int tower = idx2 >> 12;
    const int bxw = idx2 & 4095;
    const float* w = tower? w2 : w1;
    const float* g = tower? g2 : g1;
    const float* be = tower? be2 : be1;
    size_t idx = ((size_t)bxw*256 + t)*8;
    const int k = (int)(idx & (FLATn-1));
    float4 w0 = *(const float4*)(w + idx);
    float4 w1v = *(const float4*)(w + idx + 4);
    float4 g0 = *(const float4*)(g + k);
    float4 g1v = *(const float4*)(g + k + 4);
    float4 e0 = *(const float4*)(be + k);
    float4 e1v = *(const float4*)(be + k + 4);
    float a[8] = {w0.x*g0.x, w0.y*g0.y, w0.z*g0.z, w0.w*g0.w,
                  w1v.x*g1v.x, w1v.y*g1v.y, w1v.z*g1v.z, w1v.w*g1v.w};
    uint4 hv;
    pack8hi(a, hv);
    *(uint4*)(W16 + (size_t)tower*TE + idx) = hv;
    float s = w0.x*e0.x + w0.y*e0.y + w0.z*e0.z + w0.w*e0.w
            + w1v.x*e1v.x + w1v.y*e1v.y + w1v.z*e1v.z + w1v.w*e1v.w;
    sm[t] = s; __syncthreads();
    for (int off=128; off>0; off>>=1){
      if (t < off) sm[t] += sm[t+off];
      __syncthreads();
    }
    if (t==0){
      const int o = (int)(idx >> 14);
      atomicAdd(&biasP[tower*HIDn + o], sm[0]);
    }
  }
}

__device__ __forceinline__ void glds16(const void* g, void* l){
  __builtin_amdgcn_global_load_lds((const __attribute__((address_space(1))) uint32_t*)g,
                                   (__attribute__((address_space(3))) uint32_t*)l, 16, 0, 0);
}

// MFMA GEMM (BM=128, BN=512, BK=64 as two 32-k sub-steps per barrier round, 8 waves 2m x 4n),
// A+B double-buffered, 160KB LDS, single barrier per round (64 rounds vs 128).
// Pure bf16 (1-term). [R13 schedule, paired sub-steps] 256 blocks: bid&7=tower*4+kc, bid>>3=mi
__global__ __launch_bounds__(512) void k_gemm1m(
    const float* __restrict__ x, const int* __restrict__ cnt,
    const float* __restrict__ mu, const float* __restrict__ rinv,
    const ushort* __restrict__ W16,
    float* __restrict__ hp){
  __shared__ uint4 A_lds[2][2][8][64];      // (buf, sub, rb, lane) 32KB
  __shared__ uint4 B_lds[2][2][32][64];     // (buf, sub, cb, lane) 128KB
  const int t = threadIdx.x;
  const int lane = t & 63;
  const int wid = t >> 6;
  const int wm = wid >> 2, wn = wid & 3;

  const int bid = blockIdx.x;
  const int kc = bid & 3;
  const int tower = (bid >> 2) & 1;
  const int mi = bid >> 3;
  const int b0 = mi*128;
  const size_t TE = (size_t)HIDn*FLATn;
  const ushort* Wb = W16 + (size_t)tower*TE;

  const int r = t>>2, seg = t&3;
  const int brow = b0 + r;
  const int cbr = cnt[brow];
  const float mur = mu[brow];
  const float rir = rinv[brow];
  const float* xrow = x + (size_t)brow*FLATn;
  const int rb_s = r>>4;
  const int lane_s = (r&15) + 16*seg;

  f32x4 acc[4][8];
  #pragma unroll
  for (int i=0;i<4;i++)
    #pragma unroll
    for (int j=0;j<8;j++)
      acc[i][j] = (f32x4){0.f,0.f,0.f,0.f};

  // kt32 counts 32-k units (0..127)
  auto loadA = [&](int kt32, float* dst){
    const int k0 = kc*4096 + kt32*32;
    const int m = k0 >> 10;
    const int d0 = (k0 & 1023) + seg*8;
    const bool valid = m < cbr;
    int sm_ = tower ? (cbr-1-m) : m;
    if (!valid) sm_ = 0;
    const float* src = xrow + sm_*Dn + d0;
    float4 v0 = *(const float4*)(src);
    float4 v1 = *(const float4*)(src+4);
    float vv[8] = {v0.x,v0.y,v0.z,v0.w,v1.x,v1.y,v1.z,v1.w};
    #pragma unroll
    for (int j=0;j<8;j++){
      float a = valid ? vv[j] : 0.f;
      dst[j] = (a - mur)*rir;
    }
  };

  auto writeA = [&](const float* sv, int buf, int sub){
    uint4 hv;
    pack8hi(sv, hv);
    A_lds[buf][sub][rb_s][lane_s] = hv;
  };

  auto stageB = [&](int kt32, int buf, int sub){
    const int k0 = kc*4096 + kt32*32;
    const int col_l = lane & 15;
    const int kk_l = k0 + (lane>>4)*8;
    #pragma unroll
    for (int q=0;q<4;q++){
      int cb = wid*4 + q;         // 0..31
      const ushort* src = Wb + (size_t)(cb*16 + col_l)*FLATn + kk_l;
      glds16((const void*)src, (void*)&B_lds[buf][sub][cb][0]);
    }
  };

  auto compute = [&](int buf, int sub){
    short8 ah[4];
    #pragma unroll
    for (int mf=0; mf<4; ++mf)
      ah[mf] = *(const short8*)&A_lds[buf][sub][wm*4+mf][lane];
    #pragma unroll
    for (int nf=0; nf<8; ++nf){
      short8 bh = *(const short8*)&B_lds[buf][sub][wn*8+nf][lane];
      #pragma unroll
      for (int mf=0; mf<4; ++mf)
        acc[mf][nf] = __builtin_amdgcn_mfma_f32_16x16x32_bf16(ah[mf], bh, acc[mf][nf], 0, 0, 0);
    }
  };

  float av0[8], av1[8], bv0[8], bv1[8];
  loadA(0, av0);
  loadA(1, av1);
  writeA(av0, 0, 0);
  writeA(av1, 0, 1);
  stageB(0, 0, 0);
  stageB(1, 0, 1);
  loadA(2, av0);
  loadA(3, av1);
  __syncthreads();     // buf0 (both subs) ready

  #pragma unroll 1
  for (int p=0; p<64; ++p){
    const int cur = p & 1;
    if (p < 63){
      stageB(2*p+2, cur^1, 0);          // VMEM issued pre-compute
      stageB(2*p+3, cur^1, 1);
      writeA(av0, cur^1, 0);            // LDS writes into alt buffer
      writeA(av1, cur^1, 1);
      if (p < 62){
        loadA(2*p+4, bv0);              // VMEM issued pre-compute
        loadA(2*p+5, bv1);
      }
    }
    compute(cur, 0);
    compute(cur, 1);
    __syncthreads();                    // single drain point per 64-k round
    if (p < 62){
      #pragma unroll
      for (int j=0;j<8;j++){ av0[j]=bv0[j]; av1[j]=bv1[j]; }
    }
  }

  float* outp = hp + (size_t)(tower*4 + kc)*Bn*HIDn;
  #pragma unroll
  for (int mf=0; mf<4; ++mf){
    #pragma unroll
    for (int nf=0; nf<8; ++nf){
      int col = wn*128 + nf*16 + (lane&15);
      int rbase = b0 + wm*64 + mf*16 + ((lane>>4)<<2);
      #pragma unroll
      for (int rg=0; rg<4; ++rg)
        outp[(size_t)(rbase+rg)*HIDn + col] = acc[mf][nf][rg];
    }
  }
}

__global__ __launch_bounds__(256) void k_fix(const float* __restrict__ hp,
                                             const float* __restrict__ biasP,
                                             const float* __restrict__ ba1,
                                             const float* __restrict__ ba2,
                                             float* __restrict__ h1,
                                             float* __restrict__ h2){
  const int tower = blockIdx.y;
  size_t e = ((size_t)blockIdx.x*256 + threadIdx.x)*4;
  const size_t TS = (size_t)Bn*HIDn;
  const float* base = hp + (size_t)tower*4*TS;
  float4 s0 = *(const float4*)(base + e);
  float4 s1 = *(const float4*)(base + TS + e);
  float4 s2 = *(const float4*)(base + 2*TS + e);
  float4 s3 = *(const float4*)(base + 3*TS + e);
  int col = (int)(e & (HIDn-1));
  float4 bp = *(const float4*)(biasP + tower*HIDn + col);
  const float* ba = tower? ba2 : ba1;
  float4 bav = *(const float4*)(ba + col);
  float4 o;
  o.x = fmaxf(s0.x+s1.x+s2.x+s3.x+bp.x+bav.x, 0.f);
  o.y = fmaxf(s0.y+s1.y+s2.y+s3.y+bp.y+bav.y, 0.f);
  o.z = fmaxf(s0.z+s1.z+s2.z+s3.z+bp.z+bav.z, 0.f);
  o.w = fmaxf(s0.w+s1.w+s2.w+s3.w+bp.w+bav.w, 0.f);
  float* h = tower? h2 : h1;
  *(float4*)(h + e) = o;
}

// ================= FALLBACK big GEMM (fp32 VALU) =================
__global__ __launch_bounds__(256) void k_gemm1(
    const float* __restrict__ x, const int* __restrict__ cnt,
    const float* __restrict__ mu, const float* __restrict__ rinv,
    const float* __restrict__ g1, const float* __restrict__ be1,
    const float* __restrict__ w1, const float* __restrict__ bias1,
    const float* __restrict__ g2, const float* __restrict__ be2,
    const float* __restrict__ w2, const float* __restrict__ bias2,
    float* __restrict__ h1, float* __restrict__ h2) {
  const int tower = blockIdx.z;
  const float* g   = tower ? g2 : g1;
  const float* be  = tower ? be2 : be1;
  const float* w   = tower ? w2 : w1;
  const float* bia = tower ? bias2 : bias1;
  float* hout      = tower ? h2 : h1;

  __shared__ float As[32][128];
  __shared__ float Bs[32][64];

  const int t  = threadIdx.x;
  const int b0 = blockIdx.y * 128;
  const int o0 = blockIdx.x * 64;

  const int ar = t & 127;
  const int ah = t >> 7;
  const int brow = b0 + ar;
  const int cb = cnt[brow];
  const float mub = mu[brow];
  const float rb  = rinv[brow];
  const float* xrow = x + (size_t)brow * FLATn;

  const int bc = t & 63;
  const int bp = t >> 6;
  const float* wrow = w + (size_t)(o0 + bc) * FLATn;

  const int tx = t & 15, ty = t >> 4;
  const int c0 = tx*4, r0 = ty*8;

  float acc[8][4];
  #pragma unroll
  for (int i=0;i<8;i++){
    #pragma unroll
    for (int j=0;j<4;j++) acc[i][j]=0.f;
  }

  for (int kt=0; kt<FLATn/32; ++kt){
    const int k0 = kt*32;
    const int m  = k0 >> 10;
    const int d0 = k0 & 1023;
    {
      const int sm_ = tower ? (cb-1-m) : m;
      const bool valid = (m < cb);
      const float* src = xrow + sm_*Dn + d0 + ah*16;
      const float* gk  = g  + k0 + ah*16;
      const float* bk  = be + k0 + ah*16;
      #pragma unroll
      for (int q=0;q<4;q++){
        float4 v = valid ? *(const float4*)(src + q*4) : make_float4(0.f,0.f,0.f,0.f);
        float4 gg = *(const float4*)(gk + q*4);
        float4 bb = *(const float4*)(bk + q*4);
        int kk = ah*16 + q*4;
        As[kk+0][ar] = (v.x - mub)*rb*gg.x + bb.x;
        As[kk+1][ar] = (v.y - mub)*rb*gg.y + bb.y;
        As[kk+2][ar] = (v.z - mub)*rb*gg.z + bb.z;
        As[kk+3][ar] = (v.w - mub)*rb*gg.w + bb.w;
      }
    }
    {
      const float* srcw = wrow + k0 + bp*8;
      #pragma unroll
      for (int q=0;q<2;q++){
        float4 v = *(const float4*)(srcw + q*4);
        int kk = bp*8 + q*4;
        Bs[kk+0][bc]=v.x; Bs[kk+1][bc]=v.y; Bs[kk+2][bc]=v.z; Bs[kk+3][bc]=v.w;
      }
    }
    __syncthreads();
    #pragma unroll
    for (int kk=0;kk<32;kk++){
      float a[8], bb4[4];
      *(float4*)&a[0] = *(const float4*)&As[kk][r0];
      *(float4*)&a[4] = *(const float4*)&As[kk][r0+4];
      *(float4*)&bb4[0] = *(const float4*)&Bs[kk][c0];
      #pragma unroll
      for (int i=0;i<8;i++){
        #pragma unroll
        for (int j=0;j<4;j++) acc[i][j] += a[i]*bb4[j];
      }
    }
    __syncthreads();
  }
  float4 bv = *(const float4*)(bia + o0 + c0);
  #pragma unroll
  for (int i=0;i<8;i++){
    float4 ov;
    ov.x = fmaxf(acc[i][0]+bv.x, 0.f);
    ov.y = fmaxf(acc[i][1]+bv.y, 0.f);
    ov.z = fmaxf(acc[i][2]+bv.z, 0.f);
    ov.w = fmaxf(acc[i][3]+bv.w, 0.f);
    *(float4*)(hout + (size_t)(b0+r0+i)*HIDn + o0 + c0) = ov;
  }
}

// ---------------- second linear (+ fused batch-mean accumulation) ----------------
__global__ __launch_bounds__(256) void k_gemm2(
    const float* __restrict__ h1, const float* __restrict__ h2,
    const float* __restrict__ wb1, const float* __restrict__ bb1,
    const float* __restrict__ wb2, const float* __restrict__ bb2,
    float* __restrict__ F_H, float* __restrict__ F_G,
    float* __restrict__ muF) {
  const int tower = blockIdx.z;
  const float* A   = tower ? h2 : h1;
  const float* w   = tower ? wb2 : wb1;
  const float* bia = tower ? bb2 : bb1;
  float* F         = tower ? F_G : F_H;

  __shared__ float As[32][128];
  __shared__ float Bs[32][64];

  const int t  = threadIdx.x;
  const int b0 = blockIdx.y * 128;
  const int o0 = blockIdx.x * 64;

  const int ar = t & 127;
  const int ah = t >> 7;
  const float* arow = A + (size_t)(b0+ar)*HIDn;
  const int bc = t & 63;
  const int bp = t >> 6;
  const float* wrow = w + (size_t)(o0+bc)*HIDn;

  const int tx = t & 15, ty = t >> 4;
  const int c0 = tx*4, r0 = ty*8;

  float acc[8][4];
  #pragma unroll
  for (int i=0;i<8;i++){
    #pragma unroll
    for (int j=0;j<4;j++) acc[i][j]=0.f;
  }

  for (int kt=0; kt<HIDn/32; ++kt){
    const int k0 = kt*32;
    #pragma unroll
    for (int q=0;q<4;q++){
      float4 v = *(const float4*)(arow + k0 + ah*16 + q*4);
      int kk = ah*16+q*4;
      As[kk+0][ar]=v.x; As[kk+1][ar]=v.y; As[kk+2][ar]=v.z; As[kk+3][ar]=v.w;
    }
    #pragma unroll
    for (int q=0;q<2;q++){
      float4 v = *(const float4*)(wrow + k0 + bp*8 + q*4);
      int kk = bp*8+q*4;
      Bs[kk+0][bc]=v.x; Bs[kk+1][bc]=v.y; Bs[kk+2][bc]=v.z; Bs[kk+3][bc]=v.w;
    }
    __syncthreads();
    #pragma unroll
    for (int kk=0;kk<32;kk++){
      float a[8], bb4[4];
      *(float4*)&a[0] = *(const float4*)&As[kk][r0];
      *(float4*)&a[4] = *(const float4*)&As[kk][r0+4];
      *(float4*)&bb4[0] = *(const float4*)&Bs[kk][c0];
      #pragma unroll
      for (int i=0;i<8;i++){
        #pragma unroll
        for (int j=0;j<4;j++) acc[i][j] += a[i]*bb4[j];
      }
    }
    __syncthreads();
  }
  float4 bv = *(const float4*)(bia + o0 + c0);
  float cs[4];
  #pragma unroll
  for (int j=0;j<4;j++) cs[j]=0.f;
  #pragma unroll
  for (int i=0;i<8;i++){
    float4 ov;
    ov.x = acc[i][0]+bv.x;
    ov.y = acc[i][1]+bv.y;
    ov.z = acc[i][2]+bv.z;
    ov.w = acc[i][3]+bv.w;
    cs[0]+=ov.x; cs[1]+=ov.y; cs[2]+=ov.z; cs[3]+=ov.w;
    *(float4*)(F + (size_t)(b0+r0+i)*OUTn + o0 + c0) = ov;
  }
  float* red = &As[0][0];
  #pragma unroll
  for (int j=0;j<4;j++) red[ty*64 + c0 + j] = cs[j];
  __syncthreads();
  if (ty==0){
    #pragma unroll
    for (int j=0;j<4;j++){
      float tot=0.f;
      for (int q=0;q<16;q++) tot += red[q*64 + c0 + j];
      atomicAdd(&muF[tower*OUTn + o0 + c0 + j], tot);
    }
  }
}

// ---------------- covariance partials ----------------
__global__ __launch_bounds__(256) void k_covpart(const float* __restrict__ F_H,
                                                 const float* __restrict__ F_G,
                                                 float* __restrict__ covPart){
  const int s  = blockIdx.y;
  const int kc = blockIdx.x;
  const float* F1 = (s==1)? F_G : F_H;
  const float* F2 = (s==0)? F_H : F_G;
  __shared__ float A1[32][128], A2[32][128];
  const int t = threadIdx.x;
  const int tx = t & 15, ty = t >> 4;
  const int i0 = ty*8, j0 = tx*8;
  float acc[8][8];
  #pragma unroll
  for (int i=0;i<8;i++){
    #pragma unroll
    for (int j=0;j<8;j++) acc[i][j]=0.f;
  }
  const int kr = t >> 3;
  const int kp = (t & 7) * 16;
  for (int sub=0; sub<4; ++sub){
    const int kbase = kc*128 + sub*32;
    const float* p1 = F1 + (size_t)(kbase + kr)*OUTn + kp;
    const float* p2 = F2 + (size_t)(kbase + kr)*OUTn + kp;
    #pragma unroll
    for (int q=0;q<4;q++){
      *(float4*)&A1[kr][kp + q*4] = *(const float4*)(p1 + q*4);
      *(float4*)&A2[kr][kp + q*4] = *(const float4*)(p2 + q*4);
    }
    __syncthreads();
    #pragma unroll
    for (int kk=0;kk<32;kk++){
      float a[8], b[8];
      *(float4*)&a[0] = *(const float4*)&A1[kk][i0];
      *(float4*)&a[4] = *(const float4*)&A1[kk][i0+4];
      *(float4*)&b[0] = *(const float4*)&A2[kk][j0];
      *(float4*)&b[4] = *(const float4*)&A2[kk][j0+4];
      #pragma unroll
      for (int i=0;i<8;i++){
        #pragma unroll
        for (int j=0;j<8;j++) acc[i][j] += a[i]*b[j];
      }
    }
    __syncthreads();
  }
  float* outp = covPart + (size_t)(s*32 + kc)*OUTn*OUTn;
  #pragma unroll
  for (int i=0;i<8;i++){
    #pragma unroll
    for (int j=0;j<8;j+=4){
      *(float4*)(outp + (size_t)(i0+i)*OUTn + j0 + j) =
          make_float4(acc[i][j],acc[i][j+1],acc[i][j+2],acc[i][j+3]);
    }
  }
}

// muF holds column SUMS (not means)
__global__ __launch_bounds__(256) void k_sigma(const float* __restrict__ covPart,
                                               const float* __restrict__ muF,
                                               float* __restrict__ Sigma){
  const int s = blockIdx.y;
  const int e = blockIdx.x*256 + threadIdx.x;
  const int i = e >> 7, j = e & 127;
  float acc = 0.f;
  for (int c=0;c<32;c++) acc += covPart[(size_t)(s*32+c)*16384 + e];
  const float* mu1 = muF + ((s==1)? 128 : 0);
  const float* mu2 = muF + ((s==0)? 0 : 128);
  float v = (acc - mu1[i]*mu2[j]*(1.0f/(float)Bn)) * (1.0f/(float)(Bn-1));
  if (s < 2 && i==j) v += 1e-4f;
  Sigma[(size_t)s*16384 + e] = v;
}

// ---------------- Newton-Schulz prep ----------------
__global__ __launch_bounds__(256) void k_nsprep(const float* __restrict__ Sigma,
                                                float* __restrict__ Yb,
                                                float* __restrict__ Zb,
                                                float* __restrict__ cval){
  const int s = blockIdx.x;
  const float* A = Sigma + (size_t)s*16384;
  __shared__ float As[16384];
  __shared__ float v[128], w[128];
  __shared__ float sh[4];
  const int t = threadIdx.x;
  for (int i=t;i<16384;i+=256) As[i]=A[i];
  if (t<128) v[t]=1.f;
  __syncthreads();
  float lam = 1.f;
  for (int it=0; it<12; ++it){
    const int i = t>>1, hf = t&1;
    float ss=0.f;
    const float* Ai = &As[i*128];
    for (int q=hf*64;q<hf*64+64;q++) ss += Ai[q]*v[q];
    ss += __shfl_xor(ss,1);
    if (hf==0) w[i]=ss;
    __syncthreads();
    if (t==0){
      float n2=0.f;
      for (int q2=0;q2<128;q2++) n2 += w[q2]*w[q2];
      sh[0] = sqrtf(n2);
    }
    __syncthreads();
    const float nrm = sh[0];
    lam = nrm;
    if (t<128) v[t] = w[t] / fmaxf(nrm, 1e-30f);
    __syncthreads();
  }
  const float c = 1.05f*lam + 1e-20f;
  const float invc = 1.f/c;
  float* Yp = Yb + (size_t)s*16384;
  float* Zp = Zb + (size_t)s*16384;
  for (int i=t;i<16384;i+=256){
    Yp[i] = As[i]*invc;
    Zp[i] = ((i>>7)==(i&127)) ? 1.f : 0.f;
  }
  if (t==0) cval[s]=c;
}

// ---------------- NS retiled: 32x32 C-tiles ----------------
__global__ __launch_bounds__(256) void k_ns1b(const float* __restrict__ Yb,
                                              const float* __restrict__ Zb,
                                              float* __restrict__ Tb){
  const int s = blockIdx.z;
  const float* Y = Yb + (size_t)s*16384;
  const float* Z = Zb + (size_t)s*16384;
  float* T = Tb + (size_t)s*16384;
  const int r0 = blockIdx.y*32, c0 = blockIdx.x*32;
  __shared__ float As[32][132];
  __shared__ float Bs[128][32];
  const int t = threadIdx.x;
  #pragma unroll
  for (int q=0;q<4;q++){
    int i = q*1024 + t*4;
    int row = i>>7, colx = i&127;
    *(float4*)&As[row][colx] = *(const float4*)(Z + (size_t)(r0+row)*128 + colx);
    int k = i>>5, cc = i&31;
    *(float4*)&Bs[k][cc] = *(const float4*)(Y + (size_t)k*128 + c0 + cc);
  }
  __syncthreads();
  const int r = t>>3, cg = t&7;
  float acc[4] = {0.f,0.f,0.f,0.f};
  #pragma unroll
  for (int k4=0;k4<32;k4++){
    float4 a4 = *(const float4*)&As[r][k4*4];
    float aa[4] = {a4.x,a4.y,a4.z,a4.w};
    #pragma unroll
    for (int kk=0;kk<4;kk++){
      float4 b = *(const float4*)&Bs[k4*4+kk][cg*4];
      acc[0] += aa[kk]*b.x; acc[1] += aa[kk]*b.y;
      acc[2] += aa[kk]*b.z; acc[3] += aa[kk]*b.w;
    }
  }
  const int gr = r0 + r;
  const int gc = c0 + cg*4;
  float4 o;
  o.x = ((gr==gc+0)?3.f:0.f) - acc[0];
  o.y = ((gr==gc+1)?3.f:0.f) - acc[1];
  o.z = ((gr==gc+2)?3.f:0.f) - acc[2];
  o.w = ((gr==gc+3)?3.f:0.f) - acc[3];
  *(float4*)(T + (size_t)gr*128 + gc) = o;
}

__global__ __launch_bounds__(256) void k_ns2b(const float* __restrict__ Yb,
                                              const float* __restrict__ Zb,
                                              const float* __restrict__ Tb,
                                              float* __restrict__ Ynb,
                                              float* __restrict__ Znb){
  const int s = blockIdx.z;
  const int which = blockIdx.y >> 2;
  const int r0 = (blockIdx.y & 3)*32, c0 = blockIdx.x*32;
  const float* Am = which ? (Tb + (size_t)s*16384) : (Yb + (size_t)s*16384);
  const float* Bm = which ? (Zb + (size_t)s*16384) : (Tb + (size_t)s*16384);
  float* C = which ? (Znb + (size_t)s*16384) : (Ynb + (size_t)s*16384);
  __shared__ float As[32][132];
  __shared__ float Bs[128][32];
  const int t = threadIdx.x;
  #pragma unroll
  for (int q=0;q<4;q++){
    int i = q*1024 + t*4;
    int row = i>>7, colx = i&127;
    *(float4*)&As[row][colx] = *(const float4*)(Am + (size_t)(r0+row)*128 + colx);
    int k = i>>5, cc = i&31;
    *(float4*)&Bs[k][cc] = *(const float4*)(Bm + (size_t)k*128 + c0 + cc);
  }
  __syncthreads();
  const int r = t>>3, cg = t&7;
  float acc[4] = {0.f,0.f,0.f,0.f};
  #pragma unroll
  for (int k4=0;k4<32;k4++){
    float4 a4 = *(const float4*)&As[r][k4*4];
    float aa[4] = {a4.x,a4.y,a4.z,a4.w};
    #pragma unroll
    for (int kk=0;kk<4;kk++){
      float4 b = *(const float4*)&Bs[k4*4+kk][cg*4];
      acc[0] += aa[kk]*b.x; acc[1] += aa[kk]*b.y;
      acc[2] += aa[kk]*b.z; acc[3] += aa[kk]*b.w;
    }
  }
  float4 o = make_float4(0.5f*acc[0], 0.5f*acc[1], 0.5f*acc[2], 0.5f*acc[3]);
  *(float4*)(C + (size_t)(r0+r)*128 + c0 + cg*4) = o;
}

__device__ __forceinline__ void mm_acc16(const float* __restrict__ Arow,
                                         const float* __restrict__ Bs,
                                         int c0, float* acc){
  for (int k4=0;k4<128;k4+=4){
    float4 av = *(const float4*)(Arow + k4);
    float aa[4] = {av.x, av.y, av.z, av.w};
    #pragma unroll
    for (int kk=0;kk<4;kk++){
      const float a = aa[kk];
      const float* bp = &Bs[(k4+kk)*128 + c0];
      const float4 b0 = *(const float4*)(bp);
      const float4 b1 = *(const float4*)(bp+4);
      const float4 b2 = *(const float4*)(bp+8);
      const float4 b3 = *(const float4*)(bp+12);
      acc[0]+=a*b0.x;  acc[1]+=a*b0.y;  acc[2]+=a*b0.z;  acc[3]+=a*b0.w;
      acc[4]+=a*b1.x;  acc[5]+=a*b1.y;  acc[6]+=a*b1.z;  acc[7]+=a*b1.w;
      acc[8]+=a*b2.x;  acc[9]+=a*b2.y;  acc[10]+=a*b2.z; acc[11]+=a*b2.w;
      acc[12]+=a*b3.x; acc[13]+=a*b3.y; acc[14]+=a*b3.z; acc[15]+=a*b3.w;
    }
  }
}

__global__ __launch_bounds__(256) void k_mm(const float* __restrict__ Am,
                                            const float* __restrict__ Bm,
                                            float* __restrict__ C,
                                            const float* __restrict__ cval,
                                            const int useScale,
                                            float* __restrict__ out2){
  __shared__ float Bs[16384];
  const int t = threadIdx.x;
  for (int i=t;i<16384;i+=256) Bs[i]=Bm[i];
  __syncthreads();
  const int r = blockIdx.x*32 + (t>>3);
  const int c0 = (t&7)*16;
  float acc[16];
  #pragma unroll
  for (int j=0;j<16;j++) acc[j]=0.f;
  mm_acc16(Am + (size_t)r*128, Bs, c0, acc);
  const float scale = useScale ? rsqrtf(cval[0]*cval[1]) : 1.f;
  float* Cr = C + (size_t)r*128 + c0;
  #pragma unroll
  for (int j=0;j<16;j++) Cr[j] = acc[j]*scale;
  if (out2 != nullptr){
    float* Or = out2 + (size_t)r*128 + c0;
    #pragma unroll
    for (int j=0;j<16;j++) Or[j] = acc[j]*scale;
  }
}

// ---------------- fused E=T^T T + top-10 sqrt-eigenvalues via subspace iteration ----------------
__device__ __forceinline__ void pairpq(int k, int rr, int& p, int& q){
  if (k==0){ p = 15; q = rr % 15; }
  else { p = (rr + k) % 15; q = (rr + 15 - k) % 15; }
}

__global__ __launch_bounds__(1024) void k_final3(const float* __restrict__ Tmat,
                                                 float* __restrict__ outp){
  __shared__ float Es[128*132];
  __shared__ float Tt[128*132];
  __shared__ float Vt[PB*132];
  __shared__ float Wt[PB*132];
  __shared__ float GP[PB*PB*4];
  __shared__ float Gs[PB*17];
  __shared__ float Ls[PB*17];
  __shared__ float rLs[PB];
  __shared__ float Ms[PB*17];
  __shared__ float cs_[8], sn_[8];
  __shared__ float scoreSh;

  const int t = threadIdx.x;
  for (int i=t;i<16384;i+=1024)
    Tt[(i>>7)*132 + (i&127)] = Tmat[i];
  for (int i=t;i<PB*128;i+=1024){
    uint32_t u = (uint32_t)i*2654435761u + 0x9E3779B9u;
    u ^= u>>16; u *= 0x85EBCA6Bu; u ^= u>>13;
    float rv = ((float)(u & 0xFFFF) - 32768.0f) * (1.0f/32768.0f);
    Vt[(i>>7)*132 + (i&127)] = rv;
  }
  __syncthreads();

  // E = T^T @ T
  {
    const int ei = t>>3, ej0 = (t&7)*16;
    float ea[16];
    #pragma unroll
    for (int j=0;j<16;j++) ea[j]=0.f;
    for (int k=0;k<128;k++){
      float a = Tt[k*132 + ei];
      #pragma unroll
      for (int j=0;j<16;j+=4){
        float4 b = *(const float4*)&Tt[k*132 + ej0 + j];
        ea[j]+=a*b.x; ea[j+1]+=a*b.y; ea[j+2]+=a*b.z; ea[j+3]+=a*b.w;
      }
    }
    #pragma unroll
    for (int j=0;j<16;j++) Es[ei*132 + ej0 + j] = ea[j];
  }
  __syncthreads();

  const int c  = t & 15;
  const int r0 = t >> 4;
  const int gi = t >> 6;
  const int gj = (t >> 2) & 15;
  const int gq = t & 3;

  for (int it=0; it<=SSI; ++it){
    float a0=0.f, a1=0.f;
    {
      const float* vr = &Vt[c*132];
      const float* e0 = &Es[r0*132];
      const float* e1 = &Es[(r0+64)*132];
      #pragma unroll
      for (int k4=0;k4<32;k4++){
        float4 vv = *(const float4*)(vr + k4*4);
        float4 x0 = *(const float4*)(e0 + k4*4);
        float4 x1 = *(const float4*)(e1 + k4*4);
        a0 += x0.x*vv.x + x0.y*vv.y + x0.z*vv.z + x0.w*vv.w;
        a1 += x1.x*vv.x + x1.y*vv.y + x1.z*vv.z + x1.w*vv.w;
      }
    }
    Wt[c*132 + r0] = a0;
    Wt[c*132 + r0 + 64] = a1;
    __syncthreads();

    if (it == SSI) break;

    {
      float s = 0.f;
      const float* wi = &Wt[gi*132 + gq*32];
      const float* wj = &Wt[gj*132 + gq*32];
      #pragma unroll
      for (int k4=0;k4<8;k4++){
        float4 va = *(const float4*)(wi + k4*4);
        float4 vb = *(const float4*)(wj + k4*4);
        s += va.x*vb.x + va.y*vb.y + va.z*vb.z + va.w*vb.w;
      }
      GP[(gi*16+gj)*4 + gq] = s;
    }
    __syncthreads();
    if (t < 256){
      int i = t>>4, j = t&15;
      float g = GP[(i*16+j)*4+0]+GP[(i*16+j)*4+1]+GP[(i*16+j)*4+2]+GP[(i*16+j)*4+3];
      if (i==j) g *= 1.0000012f;
      Gs[i*17+j] = g;
    }
    __syncthreads();

    if (t < 64){
      const int j = t & 15;
      float g[PB], l[PB];
      #pragma unroll
      for (int i=0;i<PB;i++) g[i] = Gs[j*17+i];
      const float g00 = Gs[0];
      const float floorv = fmaxf(1e-12f*g00, 1e-30f);
      #pragma unroll
      for (int k=0;k<PB;k++){
        float dkk = __shfl(g[k], k);
        dkk = sqrtf(fmaxf(dkk, floorv));
        float ljk = g[k] / dkk;
        l[k] = ljk;
        #pragma unroll
        for (int i2=0;i2<PB;i2++){
          if (i2 > k) g[i2] -= ljk * __shfl(ljk, i2);
        }
      }
      if (t < 16){
        #pragma unroll
        for (int k=0;k<PB;k++) Ls[j*17+k] = (k<=j)? l[k] : 0.f;
        rLs[j] = 1.f / l[j];
      }
    }
    __syncthreads();

    if (t < 128){
      const int r = t;
      float w[PB], y[PB];
      #pragma unroll
      for (int i=0;i<PB;i++) w[i] = Wt[i*132 + r];
      #pragma unroll
      for (int i=0;i<PB;i++){
        float a = w[i];
        #pragma unroll
        for (int q2=0;q2<PB;q2++){
          if (q2 < i) a -= Ls[i*17+q2] * y[q2];
        }
        y[i] = a * rLs[i];
      }
      #pragma unroll
      for (int i=0;i<PB;i++) Vt[i*132 + r] = y[i];
    }
    __syncthreads();
  }

  {
    float s = 0.f;
    const float* vi = &Vt[gi*132 + gq*32];
    const float* wj = &Wt[gj*132 + gq*32];
    #pragma unroll
    for (int k4=0;k4<8;k4++){
      float4 va = *(const float4*)(vi + k4*4);
      float4 vb = *(const float4*)(wj + k4*4);
      s += va.x*vb.x + va.y*vb.y + va.z*vb.z + va.w*vb.w;
    }
    GP[(gi*16+gj)*4 + gq] = s;
  }
  __syncthreads();
  if (t < 256){
    int i = t>>4, j = t&15;
    Gs[i*17+j] = GP[(i*16+j)*4+0]+GP[(i*16+j)*4+1]+GP[(i*16+j)*4+2]+GP[(i*16+j)*4+3];
  }
  __syncthreads();
  if (t < 256){
    int i = t>>4, j = t&15;
    Ms[i*17+j] = 0.5f*(Gs[i*17+j] + Gs[j*17+i]);
  }
  __syncthreads();

  if (t < 64){
    volatile float* M = Ms;
    const int c16 = t & 15;
    const int kk0 = t >> 4;
    for (int sweep=0; sweep<7; ++sweep){
      for (int rr=0; rr<15; ++rr){
        if (t < 8){
          int p, q; pairpq(t, rr, p, q);
          float app = M[p*17+p], aqq = M[q*17+q], apq = M[p*17+q];
          float cc=1.f, ss=0.f;
          float denom = fabsf(app)+fabsf(aqq);
          if (fabsf(apq) > 1e-12f*denom + 1e-32f){
            float tau = (aqq - app) / (2.f*apq);
            float tt = ((tau>=0.f)?1.f:-1.f) / (fabsf(tau) + sqrtf(1.f + tau*tau));
            cc = rsqrtf(1.f + tt*tt);
            ss = tt*cc;
          }
          cs_[t] = cc; sn_[t] = ss;
        }
        wsync();
        #pragma unroll
        for (int kx=0; kx<2; kx++){
          int k = kk0 + kx*4;
          int p, q; pairpq(k, rr, p, q);
          float cc = cs_[k], ss = sn_[k];
          float mp = M[p*17+c16], mq = M[q*17+c16];
          M[p*17+c16] = cc*mp - ss*mq;
          M[q*17+c16] = ss*mp + cc*mq;
        }
        wsync();
        #pragma unroll
        for (int kx=0; kx<2; kx++){
          int k = kk0 + kx*4;
          int p, q; pairpq(k, rr, p, q);
          float cc = cs_[k], ss = sn_[k];
          float mp = M[c16*17+p], mq = M[c16*17+q];
          M[c16*17+p] = cc*mp - ss*mq;
          M[c16*17+q] = ss*mp + cc*mq;
        }
        wsync();
      }
    }
    if (t < 16){
      float di = M[t*17+t];
      int cnt2 = 0;
      #pragma unroll
      for (int j=0;j<16;j++){
        float dj = M[j*17+j];
        cnt2 += (dj > di || (dj == di && j < t)) ? 1 : 0;
      }
      float qc = (cnt2 < 10) ? sqrtf(fmaxf(di, 0.f)) : 0.f;
      #pragma unroll
      for (int off=8;off>0;off>>=1) qc += __shfl_down(qc, off);
      if (t==0){
        float qv = qc * 0.1f;
        scoreSh = 1.f/(1.f+expf(-qv));
      }
    }
  }
  __syncthreads();
  const float sc = scoreSh;
  for (int i=t;i<Bn;i+=1024) outp[i] = sc;
}

extern "C" void kernel_launch(void* const* d_in, const int* in_sizes, int n_in,
                              void* d_out, int out_size, void* d_ws, size_t ws_size,
                              hipStream_t stream) {
  (void)in_sizes; (void)n_in; (void)out_size;
  const float* x     = (const float*)d_in[0];
  const int*   mask  = (const int*)d_in[1];
  const float* ln1_g = (const float*)d_in[2];
  const float* ln1_b = (const float*)d_in[3];
  const float* w1a   = (const float*)d_in[4];
  const float* b1a   = (const float*)d_in[5];
  const float* w1b   = (const float*)d_in[6];
  const float* b1b   = (const float*)d_in[7];
  const float* ln2_g = (const float*)d_in[8];
  const float* ln2_b = (const float*)d_in[9];
  const float* w2a   = (const float*)d_in[10];
  const float* b2a   = (const float*)d_in[11];
  const float* w2b   = (const float*)d_in[12];
  const float* b2b   = (const float*)d_in[13];
  float* out = (float*)d_out;

  char* ws = (char*)d_ws;
  float* mu      = (float*)(ws);
  float* rinv    = (float*)(ws + (16<<10));
  int*   cnt     = (int*)  (ws + (32<<10));
  float* muF     = (float*)(ws + (48<<10));
  float* cval    = (float*)(ws + (52<<10));
  float* biasP   = (float*)(ws + (56<<10));
  float* Sigma   = (float*)(ws + (128<<10));
  const size_t nsOff = (size_t)512<<10;
  float* nsY0 = (float*)(ws + nsOff);
  float* nsY1 = (float*)(ws + nsOff + (128<<10));
  float* nsZ0 = (float*)(ws + nsOff + (256<<10));
  float* nsZ1 = (float*)(ws + nsOff + (384<<10));
  float* nsT  = (float*)(ws + nsOff + (512<<10));
  float* tmpM = (float*)(ws + nsOff + (640<<10));
  float* Tmat = (float*)(ws + nsOff + (704<<10));
  float* F_H  = (float*)(ws + ((size_t)2<<20));
  float* F_G  = (float*)(ws + ((size_t)4<<20));
  float* h1   = (float*)(ws + ((size_t)6<<20));
  float* h2   = (float*)(ws + ((size_t)14<<20));
  float* covPart = (float*)(ws + ((size_t)6<<20));
  float*  hp  = (float*)(ws + ((size_t)24<<20));
  ushort* W16 = (ushort*)(ws + ((size_t)88<<20));

  const bool fast = ws_size >= ((size_t)153<<20);

  // zero muF (col-sum accumulators), cval, biasP
  hipMemsetAsync((void*)(ws + (48<<10)), 0, (12<<10), stream);

  if (fast){
    k_pre<<<12288, 256, 0, stream>>>(x, mask, mu, rinv, cnt,
        w1a, w2a, ln1_g, ln2_g, ln1_b, ln2_b, W16, biasP);
    k_gemm1m<<<256, 512, 0, stream>>>(x, cnt, mu, rinv, W16, hp);
    k_fix<<<dim3(2048,2), 256, 0, stream>>>(hp, biasP, b1a, b2a, h1, h2);
  } else {
    k_stats<<<Bn, 256, 0, stream>>>(x, mask, mu, rinv, cnt);
    k_gemm1<<<dim3(8,32,2), 256, 0, stream>>>(x, cnt, mu, rinv,
        ln1_g, ln1_b, w1a, b1a, ln2_g, ln2_b, w2a, b2a, h1, h2);
  }
  k_gemm2<<<dim3(2,32,2), 256, 0, stream>>>(h1, h2, w1b, b1b, w2b, b2b, F_H, F_G, muF);
  k_covpart<<<dim3(32,3), 256, 0, stream>>>(F_H, F_G, covPart);
  k_sigma<<<dim3(64,3), 256, 0, stream>>>(covPart, muF, Sigma);
  k_nsprep<<<2, 256, 0, stream>>>(Sigma, nsY0, nsZ0, cval);

  float* Ycur = nsY0; float* Zcur = nsZ0; float* Yalt = nsY1; float* Zalt = nsZ1;
  for (int it=0; it<NS_ITERS; ++it){
    k_ns1b<<<dim3(4,4,2), 256, 0, stream>>>(Ycur, Zcur, nsT);
    k_ns2b<<<dim3(4,8,2), 256, 0, stream>>>(Ycur, Zcur, nsT, Yalt, Zalt);
    float* ty_ = Ycur; Ycur = Yalt; Yalt = ty_;
    float* tz_ = Zcur; Zcur = Zalt; Zalt = tz_;
  }

  k_mm<<<4, 256, 0, stream>>>(Zcur, Sigma + 2*16384, tmpM, cval, 0, nullptr);
  k_mm<<<4, 256, 0, stream>>>(tmpM, Zcur + 16384, Tmat, cval, 1, out + Bn);
  k_final3<<<1, 1024, 0, stream>>>(Tmat, out);
}